// Round 1
// baseline (4955.664 us; speedup 1.0000x reference)
//
#include <hip/hip_runtime.h>
#include <math.h>

#define TPB 256

// ---------------- GCN norm ----------------
__global__ void deg_kernel(const int* __restrict__ col, float* __restrict__ deg, int E) {
    int e = blockIdx.x * blockDim.x + threadIdx.x;
    if (e < E) atomicAdd(&deg[col[e]], 1.0f);
}

__global__ void dinv_kernel(float* __restrict__ deg, int n) {
    int i = blockIdx.x * blockDim.x + threadIdx.x;
    if (i < n) {
        float d = deg[i];
        deg[i] = (d > 0.0f) ? rsqrtf(d) : 0.0f;   // max(d,1) is a no-op when d>0 (integer counts)
    }
}

__global__ void norm_kernel(const int* __restrict__ row, const int* __restrict__ col,
                            const float* __restrict__ dinv, float* __restrict__ nrm, int E) {
    int e = blockIdx.x * blockDim.x + threadIdx.x;
    if (e < E) nrm[e] = dinv[row[e]] * dinv[col[e]];
}

// ---------------- dense GEMM: dst[k][n][f] = sum_i src[(k)?][n][i] * W[k][i][f] (+ bias[k][f]) ----------------
// K is hardcoded 2. srcPerK: 0 -> src is [N,Fin] shared across k; 1 -> src is [K,N,Fin].
__global__ void gemm_kernel(const float* __restrict__ src, const float* __restrict__ W,
                            const float* __restrict__ bias, float* __restrict__ dst,
                            int N, int Fin, int F, int srcPerK) {
    int tid = blockIdx.x * blockDim.x + threadIdx.x;
    int total = 2 * N * F;
    if (tid >= total) return;
    int f  = tid % F;
    int nk = tid / F;
    int n  = nk % N;
    int k  = nk / N;
    const float* s = src + (size_t)(srcPerK ? ((size_t)k * N + n) : (size_t)n) * Fin;
    const float* w = W + (size_t)k * Fin * F + f;
    float acc = bias ? bias[k * F + f] : 0.0f;
#pragma unroll 8
    for (int i = 0; i < Fin; ++i) acc = fmaf(s[i], w[(size_t)i * F], acc);
    dst[tid] = acc;   // tid == (k*N + n)*F + f
}

// ---------------- edge propagation: dst[k][col][f] += src[k][row][f] * norm ----------------
__global__ void edge_kernel(const int* __restrict__ row, const int* __restrict__ col,
                            const float* __restrict__ nrm,
                            const float* __restrict__ src, float* __restrict__ dst,
                            int E, int N, int F) {
    long long tid = (long long)blockIdx.x * blockDim.x + threadIdx.x;
    long long total = (long long)E * F;
    if (tid >= total) return;
    int f = (int)(tid % F);
    int e = (int)(tid / F);
    int r = row[e];
    int c = col[e];
    float nm = nrm[e];
    size_t so = (size_t)r * F + f;
    size_t dofs = (size_t)c * F + f;
    size_t ks = (size_t)N * F;
    atomicAdd(&dst[dofs],      src[so]      * nm);
    atomicAdd(&dst[dofs + ks], src[so + ks] * nm);
}

__global__ void relu_kernel(float* __restrict__ p, int n) {
    int i = blockIdx.x * blockDim.x + threadIdx.x;
    if (i < n) p[i] = fmaxf(p[i], 0.0f);
}

// h[n][f] = relu(0.5*(src[0][n][f] + src[1][n][f]))
__global__ void mean_relu_kernel(const float* __restrict__ src, float* __restrict__ h, int NF) {
    int i = blockIdx.x * blockDim.x + threadIdx.x;
    if (i < NF) h[i] = fmaxf(0.5f * (src[i] + src[(size_t)NF + i]), 0.0f);
}

// out[n][c] = log_softmax_c( 0.5*(src[0][n][c] + src[1][n][c]) )
__global__ void logsoftmax_kernel(const float* __restrict__ src, float* __restrict__ out, int N, int C) {
    int n = blockIdx.x * blockDim.x + threadIdx.x;
    if (n >= N) return;
    const float* a = src + (size_t)n * C;
    const float* b = src + (size_t)N * C + (size_t)n * C;
    float v[64];
    float mx = -1e30f;
    for (int c = 0; c < C; ++c) {
        float t = 0.5f * (a[c] + b[c]);
        v[c] = t;
        mx = fmaxf(mx, t);
    }
    float s = 0.0f;
    for (int c = 0; c < C; ++c) s += expf(v[c] - mx);
    float ls = logf(s);
    for (int c = 0; c < C; ++c) out[(size_t)n * C + c] = v[c] - mx - ls;
}

extern "C" void kernel_launch(void* const* d_in, const int* in_sizes, int n_in,
                              void* d_out, int out_size, void* d_ws, size_t ws_size,
                              hipStream_t stream) {
    const float* x       = (const float*)d_in[0];
    const int*   ei      = (const int*)  d_in[1];
    const float* w1_init = (const float*)d_in[2];
    const float* w1      = (const float*)d_in[3];
    const float* w1_root = (const float*)d_in[4];
    const float* b1      = (const float*)d_in[5];
    const float* w2_init = (const float*)d_in[6];
    const float* w2      = (const float*)d_in[7];
    const float* w2_root = (const float*)d_in[8];
    const float* b2      = (const float*)d_in[9];

    const int Fin1 = 128, F1 = 64, F2 = 41;
    int N = in_sizes[0] / Fin1;          // 100000
    int E = in_sizes[1] / 2;             // 1600000
    const int* row = ei;
    const int* col = ei + E;

    // workspace carve-out
    char* ws = (char*)d_ws;
    size_t off = 0;
    auto carve = [&](size_t bytes) -> void* {
        void* p = ws + off;
        off += (bytes + 255) & ~(size_t)255;
        return p;
    };
    float* deg  = (float*)carve((size_t)N * 4);           // reused as dinv in-place
    float* nrm  = (float*)carve((size_t)E * 4);
    float* bufA = (float*)carve((size_t)2 * N * F1 * 4);  // 51.2 MB, reused by layer 2
    float* bufB = (float*)carve((size_t)2 * N * F1 * 4);  // 51.2 MB, reused by layer 2
    float* h    = (float*)carve((size_t)N * F1 * 4);      // 25.6 MB

    // ---- norm ----
    hipMemsetAsync(deg, 0, (size_t)N * 4, stream);
    deg_kernel <<<(E + TPB - 1) / TPB, TPB, 0, stream>>>(col, deg, E);
    dinv_kernel<<<(N + TPB - 1) / TPB, TPB, 0, stream>>>(deg, N);
    norm_kernel<<<(E + TPB - 1) / TPB, TPB, 0, stream>>>(row, col, deg, nrm, E);

    // ---- layer 1 (Fin=128 -> F=64) ----
    int tot1 = 2 * N * F1;
    int gb1  = (tot1 + TPB - 1) / TPB;
    long long ew1 = (long long)E * F1;
    int egb1 = (int)((ew1 + TPB - 1) / TPB);

    // out = x @ w1_init
    gemm_kernel<<<gb1, TPB, 0, stream>>>(x, w1_init, nullptr, bufA, N, Fin1, F1, 0);
    // t = 0
    gemm_kernel<<<gb1, TPB, 0, stream>>>(x, w1_root, b1, bufB, N, Fin1, F1, 0);
    edge_kernel<<<egb1, TPB, 0, stream>>>(row, col, nrm, bufA, bufB, E, N, F1);
    relu_kernel<<<gb1, TPB, 0, stream>>>(bufB, tot1);
    // t = 1
    gemm_kernel<<<gb1, TPB, 0, stream>>>(bufB, w1, nullptr, bufA, N, F1, F1, 1);
    gemm_kernel<<<gb1, TPB, 0, stream>>>(x, w1_root + (size_t)2 * Fin1 * F1, b1 + 2 * F1,
                                         bufB, N, Fin1, F1, 0);
    edge_kernel<<<egb1, TPB, 0, stream>>>(row, col, nrm, bufA, bufB, E, N, F1);
    relu_kernel<<<gb1, TPB, 0, stream>>>(bufB, tot1);
    // h = relu(mean_k)
    int nf1 = N * F1;
    mean_relu_kernel<<<(nf1 + TPB - 1) / TPB, TPB, 0, stream>>>(bufB, h, nf1);

    // ---- layer 2 (Fin=64 -> F=41) ----
    int tot2 = 2 * N * F2;
    int gb2  = (tot2 + TPB - 1) / TPB;
    long long ew2 = (long long)E * F2;
    int egb2 = (int)((ew2 + TPB - 1) / TPB);

    gemm_kernel<<<gb2, TPB, 0, stream>>>(h, w2_init, nullptr, bufA, N, F1, F2, 0);
    // t = 0
    gemm_kernel<<<gb2, TPB, 0, stream>>>(h, w2_root, b2, bufB, N, F1, F2, 0);
    edge_kernel<<<egb2, TPB, 0, stream>>>(row, col, nrm, bufA, bufB, E, N, F2);
    relu_kernel<<<gb2, TPB, 0, stream>>>(bufB, tot2);
    // t = 1
    gemm_kernel<<<gb2, TPB, 0, stream>>>(bufB, w2, nullptr, bufA, N, F2, F2, 1);
    gemm_kernel<<<gb2, TPB, 0, stream>>>(h, w2_root + (size_t)2 * F1 * F2, b2 + 2 * F2,
                                         bufB, N, F1, F2, 0);
    edge_kernel<<<egb2, TPB, 0, stream>>>(row, col, nrm, bufA, bufB, E, N, F2);
    relu_kernel<<<gb2, TPB, 0, stream>>>(bufB, tot2);

    // ---- mean over k + log_softmax ----
    logsoftmax_kernel<<<(N + TPB - 1) / TPB, TPB, 0, stream>>>(bufB, (float*)d_out, N, F2);
}

// Round 2
// 2575.885 us; speedup vs baseline: 1.9239x; 1.9239x over previous
//
#include <hip/hip_runtime.h>
#include <math.h>

#define TPB 256

// ==================== GCN norm + CSR build ====================
__global__ void count_kernel(const int* __restrict__ col, int* __restrict__ cnt, int E) {
    int e = blockIdx.x * blockDim.x + threadIdx.x;
    if (e < E) atomicAdd(&cnt[col[e]], 1);
}

__global__ void dinv_kernel(const int* __restrict__ cnt, float* __restrict__ dinv, int n) {
    int i = blockIdx.x * blockDim.x + threadIdx.x;
    if (i < n) {
        int d = cnt[i];
        dinv[i] = (d > 0) ? rsqrtf((float)d) : 0.0f;
    }
}

// block-level inclusive scan of cnt -> incl, per-block totals -> bsum
__global__ void scan_block(const int* __restrict__ cnt, int* __restrict__ incl,
                           int* __restrict__ bsum, int N) {
    __shared__ int s[TPB];
    int i = blockIdx.x * TPB + threadIdx.x;
    s[threadIdx.x] = (i < N) ? cnt[i] : 0;
    __syncthreads();
    for (int d = 1; d < TPB; d <<= 1) {
        int t = (threadIdx.x >= d) ? s[threadIdx.x - d] : 0;
        __syncthreads();
        s[threadIdx.x] += t;
        __syncthreads();
    }
    if (i < N) incl[i] = s[threadIdx.x];
    if (threadIdx.x == TPB - 1) bsum[blockIdx.x] = s[TPB - 1];
}

// serial exclusive scan of block sums (nb ~ 391, trivial)
__global__ void scan_bsums(int* __restrict__ bsum, int nb) {
    int acc = 0;
    for (int b = 0; b < nb; ++b) { int v = bsum[b]; bsum[b] = acc; acc += v; }
}

// rowstart[i+1] = incl[i]+bsum[b]; cursor[i] = exclusive = that - cnt[i]
__global__ void finalize_csr(const int* __restrict__ incl, const int* __restrict__ bsum,
                             const int* __restrict__ cnt, int* __restrict__ rowstart,
                             int* __restrict__ cursor, int N) {
    int i = blockIdx.x * TPB + threadIdx.x;
    if (i < N) {
        int v = incl[i] + bsum[blockIdx.x];
        rowstart[i + 1] = v;
        cursor[i] = v - cnt[i];
    }
    if (i == 0) rowstart[0] = 0;
}

__global__ void fill_csr(const int* __restrict__ row, const int* __restrict__ col,
                         const float* __restrict__ dinv, int* __restrict__ cursor,
                         int* __restrict__ srcidx, float* __restrict__ wgt, int E) {
    int e = blockIdx.x * blockDim.x + threadIdx.x;
    if (e < E) {
        int c = col[e], r = row[e];
        int p = atomicAdd(&cursor[c], 1);
        srcidx[p] = r;
        wgt[p] = dinv[r] * dinv[c];
    }
}

// ==================== tiled GEMM ====================
// dst[k][n][f] = sum_i src[(k)?][n][i] * W[k][i][f] (+ bias[k][f])
// Block: 256 threads, tile = 64 nodes x FW feats, one k per blockIdx.y.
// FINP: FIN padded to mult of 4 (zero-filled). FW: F padded to mult of 4. TXN = FW/4.
template<int FIN, int FINP, int F, int FW, int TXN>
__global__ void gemm_tiled(const float* __restrict__ src, const float* __restrict__ W,
                           const float* __restrict__ bias, float* __restrict__ dst,
                           int N, int srcPerK) {
    constexpr int M = 64;
    __shared__ float sX[M][FINP];
    __shared__ float sW[FINP][FW];
    const int k = blockIdx.y;
    const int n0 = blockIdx.x * M;
    const int t = threadIdx.x;

    const float* Wk = W + (size_t)k * FIN * F;
    for (int idx = t; idx < FINP * FW; idx += 256) {
        int i = idx / FW, f = idx % FW;
        sW[i][f] = (i < FIN && f < F) ? Wk[i * F + f] : 0.0f;
    }
    const float* sbase = src + (srcPerK ? (size_t)k * N * FIN : (size_t)0);
    for (int idx = t; idx < M * FINP; idx += 256) {
        int r = idx / FINP, i = idx % FINP;
        int n = n0 + r;
        sX[r][i] = (n < N && i < FIN) ? sbase[(size_t)n * FIN + i] : 0.0f;
    }
    __syncthreads();

    const int tx = t % TXN;
    const int ty = t / TXN;
    if (ty < 16) {
        const int f0 = tx * 4;
        const int r0 = ty * 4;
        float acc[4][4] = {};
        for (int i = 0; i < FINP; i += 4) {
            float4 w0 = *(const float4*)&sW[i + 0][f0];
            float4 w1 = *(const float4*)&sW[i + 1][f0];
            float4 w2 = *(const float4*)&sW[i + 2][f0];
            float4 w3 = *(const float4*)&sW[i + 3][f0];
#pragma unroll
            for (int a = 0; a < 4; ++a) {
                float4 s = *(const float4*)&sX[r0 + a][i];
                acc[a][0] = fmaf(s.x, w0.x, acc[a][0]);
                acc[a][1] = fmaf(s.x, w0.y, acc[a][1]);
                acc[a][2] = fmaf(s.x, w0.z, acc[a][2]);
                acc[a][3] = fmaf(s.x, w0.w, acc[a][3]);
                acc[a][0] = fmaf(s.y, w1.x, acc[a][0]);
                acc[a][1] = fmaf(s.y, w1.y, acc[a][1]);
                acc[a][2] = fmaf(s.y, w1.z, acc[a][2]);
                acc[a][3] = fmaf(s.y, w1.w, acc[a][3]);
                acc[a][0] = fmaf(s.z, w2.x, acc[a][0]);
                acc[a][1] = fmaf(s.z, w2.y, acc[a][1]);
                acc[a][2] = fmaf(s.z, w2.z, acc[a][2]);
                acc[a][3] = fmaf(s.z, w2.w, acc[a][3]);
                acc[a][0] = fmaf(s.w, w3.x, acc[a][0]);
                acc[a][1] = fmaf(s.w, w3.y, acc[a][1]);
                acc[a][2] = fmaf(s.w, w3.z, acc[a][2]);
                acc[a][3] = fmaf(s.w, w3.w, acc[a][3]);
            }
        }
#pragma unroll
        for (int a = 0; a < 4; ++a) {
            int n = n0 + r0 + a;
            if (n >= N) break;
            size_t base = ((size_t)k * N + n) * F;
#pragma unroll
            for (int b = 0; b < 4; ++b) {
                int f = f0 + b;
                if (f < F) dst[base + f] = acc[a][b] + (bias ? bias[k * F + f] : 0.0f);
            }
        }
    }
}

// ==================== CSR gather + root + relu ====================
// out[k][n][f] = relu( out[k][n][f] + sum_{e in in(n)} msg[k][src(e)][f] * w(e) )
template<int F>
__global__ void gather_kernel(const int* __restrict__ rowstart,
                              const int* __restrict__ srcidx, const float* __restrict__ wgt,
                              const float* __restrict__ msg, float* __restrict__ out, int N) {
    int gt = blockIdx.x * blockDim.x + threadIdx.x;
    int n = gt / 64;
    int lane = gt % 64;
    if (n >= N) return;
    int beg = rowstart[n], end = rowstart[n + 1];
    size_t KS = (size_t)N * F;
    float acc0 = 0.0f, acc1 = 0.0f;
    if (lane < F) {
        for (int e = beg; e < end; ++e) {
            int s = srcidx[e];
            float w = wgt[e];
            size_t so = (size_t)s * F + lane;
            acc0 = fmaf(msg[so], w, acc0);
            acc1 = fmaf(msg[so + KS], w, acc1);
        }
        size_t o = (size_t)n * F + lane;
        out[o]      = fmaxf(out[o] + acc0, 0.0f);
        out[o + KS] = fmaxf(out[o + KS] + acc1, 0.0f);
    }
}

// h[n][f] = relu(0.5*(src[0][n][f] + src[1][n][f]))
__global__ void mean_relu_kernel(const float* __restrict__ src, float* __restrict__ h, int NF) {
    int i = blockIdx.x * blockDim.x + threadIdx.x;
    if (i < NF) h[i] = fmaxf(0.5f * (src[i] + src[(size_t)NF + i]), 0.0f);
}

// out[n][c] = log_softmax_c( 0.5*(src[0][n][c] + src[1][n][c]) )
__global__ void logsoftmax_kernel(const float* __restrict__ src, float* __restrict__ out, int N, int C) {
    int n = blockIdx.x * blockDim.x + threadIdx.x;
    if (n >= N) return;
    const float* a = src + (size_t)n * C;
    const float* b = src + (size_t)N * C + (size_t)n * C;
    float v[48];
    float mx = -1e30f;
    for (int c = 0; c < C; ++c) {
        float t = 0.5f * (a[c] + b[c]);
        v[c] = t;
        mx = fmaxf(mx, t);
    }
    float s = 0.0f;
    for (int c = 0; c < C; ++c) s += expf(v[c] - mx);
    float ls = logf(s);
    for (int c = 0; c < C; ++c) out[(size_t)n * C + c] = v[c] - mx - ls;
}

extern "C" void kernel_launch(void* const* d_in, const int* in_sizes, int n_in,
                              void* d_out, int out_size, void* d_ws, size_t ws_size,
                              hipStream_t stream) {
    const float* x       = (const float*)d_in[0];
    const int*   ei      = (const int*)  d_in[1];
    const float* w1_init = (const float*)d_in[2];
    const float* w1      = (const float*)d_in[3];
    const float* w1_root = (const float*)d_in[4];
    const float* b1      = (const float*)d_in[5];
    const float* w2_init = (const float*)d_in[6];
    const float* w2      = (const float*)d_in[7];
    const float* w2_root = (const float*)d_in[8];
    const float* b2      = (const float*)d_in[9];

    const int Fin1 = 128, F1 = 64, F2 = 41;
    int N = in_sizes[0] / Fin1;          // 100000
    int E = in_sizes[1] / 2;             // 1600000
    const int* row = ei;
    const int* col = ei + E;

    char* ws = (char*)d_ws;
    size_t off = 0;
    auto carve = [&](size_t bytes) -> void* {
        void* p = ws + off;
        off += (bytes + 255) & ~(size_t)255;
        return p;
    };
    int nblkN = (N + TPB - 1) / TPB;
    int*   cnt      = (int*)  carve((size_t)N * 4);
    int*   incl     = (int*)  carve((size_t)N * 4);
    int*   rowstart = (int*)  carve((size_t)(N + 1) * 4);
    int*   cursor   = (int*)  carve((size_t)N * 4);
    int*   bsum     = (int*)  carve((size_t)nblkN * 4);
    float* dinv     = (float*)carve((size_t)N * 4);
    int*   srcidx   = (int*)  carve((size_t)E * 4);
    float* wgt      = (float*)carve((size_t)E * 4);
    float* bufA     = (float*)carve((size_t)2 * N * F1 * 4);  // 51.2 MB
    float* bufB     = (float*)carve((size_t)2 * N * F1 * 4);  // 51.2 MB
    float* h        = (float*)carve((size_t)N * F1 * 4);      // 25.6 MB

    // ---- CSR + norm ----
    hipMemsetAsync(cnt, 0, (size_t)N * 4, stream);
    count_kernel<<<(E + TPB - 1) / TPB, TPB, 0, stream>>>(col, cnt, E);
    dinv_kernel <<<nblkN, TPB, 0, stream>>>(cnt, dinv, N);
    scan_block  <<<nblkN, TPB, 0, stream>>>(cnt, incl, bsum, N);
    scan_bsums  <<<1, 1, 0, stream>>>(bsum, nblkN);
    finalize_csr<<<nblkN, TPB, 0, stream>>>(incl, bsum, cnt, rowstart, cursor, N);
    fill_csr    <<<(E + TPB - 1) / TPB, TPB, 0, stream>>>(row, col, dinv, cursor, srcidx, wgt, E);

    dim3 gg1((N + 63) / 64, 2);
    int gthr = N * 64;
    int ggb = (gthr + TPB - 1) / TPB;

    // ---- layer 1 (128 -> 64) ----
    gemm_tiled<128,128,64,64,16><<<gg1, TPB, 0, stream>>>(x, w1_init, nullptr, bufA, N, 0);
    // t=0
    gemm_tiled<128,128,64,64,16><<<gg1, TPB, 0, stream>>>(x, w1_root, b1, bufB, N, 0);
    gather_kernel<64><<<ggb, TPB, 0, stream>>>(rowstart, srcidx, wgt, bufA, bufB, N);
    // t=1
    gemm_tiled<64,64,64,64,16><<<gg1, TPB, 0, stream>>>(bufB, w1, nullptr, bufA, N, 1);
    gemm_tiled<128,128,64,64,16><<<gg1, TPB, 0, stream>>>(x, w1_root + (size_t)2 * Fin1 * F1,
                                                          b1 + 2 * F1, bufB, N, 0);
    gather_kernel<64><<<ggb, TPB, 0, stream>>>(rowstart, srcidx, wgt, bufA, bufB, N);
    // h = relu(mean_k)
    int nf1 = N * F1;
    mean_relu_kernel<<<(nf1 + TPB - 1) / TPB, TPB, 0, stream>>>(bufB, h, nf1);

    // ---- layer 2 (64 -> 41) ----
    gemm_tiled<64,64,41,44,11><<<gg1, TPB, 0, stream>>>(h, w2_init, nullptr, bufA, N, 0);
    // t=0
    gemm_tiled<64,64,41,44,11><<<gg1, TPB, 0, stream>>>(h, w2_root, b2, bufB, N, 0);
    gather_kernel<41><<<ggb, TPB, 0, stream>>>(rowstart, srcidx, wgt, bufA, bufB, N);
    // t=1
    gemm_tiled<41,44,41,44,11><<<gg1, TPB, 0, stream>>>(bufB, w2, nullptr, bufA, N, 1);
    gemm_tiled<64,64,41,44,11><<<gg1, TPB, 0, stream>>>(h, w2_root + (size_t)2 * F1 * F2,
                                                        b2 + 2 * F2, bufB, N, 0);
    gather_kernel<41><<<ggb, TPB, 0, stream>>>(rowstart, srcidx, wgt, bufA, bufB, N);

    // ---- mean over k + log_softmax ----
    logsoftmax_kernel<<<(N + TPB - 1) / TPB, TPB, 0, stream>>>(bufB, (float*)d_out, N, F2);
}

// Round 3
// 1475.504 us; speedup vs baseline: 3.3586x; 1.7458x over previous
//
#include <hip/hip_runtime.h>
#include <math.h>

#define TPB 256
typedef unsigned short ushort_t;
typedef unsigned int uint_t;

__device__ __forceinline__ float bf2f(ushort_t h) {
    return __uint_as_float(((uint_t)h) << 16);
}
__device__ __forceinline__ ushort_t f2bf(float f) {
    uint_t u = __float_as_uint(f);
    u += 0x7fff + ((u >> 16) & 1);
    return (ushort_t)(u >> 16);
}
__device__ __forceinline__ uint_t pack2(float x, float y) {
    return (uint_t)f2bf(x) | ((uint_t)f2bf(y) << 16);
}

// ==================== CSR build + GCN norm ====================
__global__ void count_kernel(const int* __restrict__ col, int* __restrict__ cnt, int E) {
    int e = blockIdx.x * blockDim.x + threadIdx.x;
    if (e < E) atomicAdd(&cnt[col[e]], 1);
}

__global__ void dinv_kernel(const int* __restrict__ cnt, float* __restrict__ dinv, int n) {
    int i = blockIdx.x * blockDim.x + threadIdx.x;
    if (i < n) {
        int d = cnt[i];
        dinv[i] = (d > 0) ? rsqrtf((float)d) : 0.0f;
    }
}

__global__ void scan_block(const int* __restrict__ cnt, int* __restrict__ incl,
                           int* __restrict__ bsum, int N) {
    __shared__ int s[TPB];
    int i = blockIdx.x * TPB + threadIdx.x;
    s[threadIdx.x] = (i < N) ? cnt[i] : 0;
    __syncthreads();
    for (int d = 1; d < TPB; d <<= 1) {
        int t = (threadIdx.x >= d) ? s[threadIdx.x - d] : 0;
        __syncthreads();
        s[threadIdx.x] += t;
        __syncthreads();
    }
    if (i < N) incl[i] = s[threadIdx.x];
    if (threadIdx.x == TPB - 1) bsum[blockIdx.x] = s[TPB - 1];
}

__global__ void scan_bsums(int* __restrict__ bsum, int nb) {
    int acc = 0;
    for (int b = 0; b < nb; ++b) { int v = bsum[b]; bsum[b] = acc; acc += v; }
}

__global__ void finalize_csr(const int* __restrict__ incl, const int* __restrict__ bsum,
                             const int* __restrict__ cnt, int* __restrict__ rowstart,
                             int* __restrict__ cursor, int N) {
    int i = blockIdx.x * TPB + threadIdx.x;
    if (i < N) {
        int v = incl[i] + bsum[blockIdx.x];
        rowstart[i + 1] = v;
        cursor[i] = v - cnt[i];
    }
    if (i == 0) rowstart[0] = 0;
}

__global__ void fill_csr(const int* __restrict__ row, const int* __restrict__ col,
                         const float* __restrict__ dinv, int* __restrict__ cursor,
                         int* __restrict__ srcidx, float* __restrict__ wgt, int E) {
    int e = blockIdx.x * blockDim.x + threadIdx.x;
    if (e < E) {
        int c = col[e], r = row[e];
        int p = atomicAdd(&cursor[c], 1);
        srcidx[p] = r;
        wgt[p] = dinv[r] * dinv[c];
    }
}

// ==================== conversion / mean kernels ====================
__global__ void cvt_kernel(const float* __restrict__ src, ushort_t* __restrict__ dst, int n) {
    int i = blockIdx.x * blockDim.x + threadIdx.x;
    if (i < n) dst[i] = f2bf(src[i]);
}

// hh[n*64+f] = bf16(0.5*(srcF[i] + srcF[i+NF])), srcF layout [k][n][64]
__global__ void mean_cvt_kernel(const float* __restrict__ srcF, ushort_t* __restrict__ hh, int NF) {
    int i = blockIdx.x * blockDim.x + threadIdx.x;
    if (i < NF) hh[i] = f2bf(0.5f * (srcF[i] + srcF[(size_t)NF + i]));
}

// ==================== concat-K GEMM ====================
// acc[k][n][f] = sum over (s1 [n][2][F1p] bf16 w/ W1 [2][F1][F]) and (s2 [n][F2] bf16 w/ W2 [2][F2][F])
// + bias[k][F]; optional relu; outputs: outF f32 [k][n][FW] and/or outH bf16 [n][2][FW].
template<int FW>   // FW: padded out feats (mult of 4), TXN=FW/4 <= 16
__global__ __launch_bounds__(256)
void gemm2(const ushort_t* __restrict__ s1, const float* __restrict__ W1, int F1, int F1p,
           const ushort_t* __restrict__ s2, const float* __restrict__ W2, int F2,
           const float* __restrict__ bias, int F, int relu, int N,
           float* __restrict__ outF, ushort_t* __restrict__ outH) {
    constexpr int M = 128;
    constexpr int TXN = FW / 4;
    __shared__ float sX[M][68];      // 64-col chunk, stride 68 breaks bank aliasing
    __shared__ float sW[64][FW];
    const int k = blockIdx.y;
    const int n0 = blockIdx.x * M;
    const int t = threadIdx.x;
    const int tx = t % TXN, ty = t / TXN;
    float acc[8][4] = {};

    for (int op = 0; op < 2; ++op) {
        const ushort_t* src = op ? s2 : s1;
        if (!src) continue;
        const int Fi = op ? F2 : F1;
        const float* Wb = op ? W2 : W1;
        const float* Wk = Wb + (size_t)k * Fi * F;
        for (int c = 0; c < Fi; c += 64) {
            int rows = Fi - c; if (rows > 64) rows = 64;
            for (int idx = t; idx < 64 * FW; idx += 256) {
                int kk = idx / FW, f = idx % FW;
                sW[kk][f] = (kk < rows && f < F) ? Wk[(size_t)(c + kk) * F + f] : 0.0f;
            }
            for (int idx = t; idx < M * 64; idx += 256) {
                int r = idx >> 6, j = idx & 63;
                int n = n0 + r;
                float v = 0.0f;
                if (j < rows && n < N) {
                    size_t rowb = op ? (size_t)n * F2 : ((size_t)n * 2 + k) * F1p;
                    v = bf2f(src[rowb + c + j]);
                }
                sX[r][j] = v;
            }
            __syncthreads();
            if (ty < 16) {
                const int f0 = tx * 4;
                for (int i = 0; i < 64; i += 4) {
                    float4 w0 = *(const float4*)&sW[i + 0][f0];
                    float4 w1 = *(const float4*)&sW[i + 1][f0];
                    float4 w2 = *(const float4*)&sW[i + 2][f0];
                    float4 w3 = *(const float4*)&sW[i + 3][f0];
#pragma unroll
                    for (int a = 0; a < 8; ++a) {
                        float4 s = *(const float4*)&sX[ty + 16 * a][i];
                        acc[a][0] = fmaf(s.x, w0.x, acc[a][0]);
                        acc[a][1] = fmaf(s.x, w0.y, acc[a][1]);
                        acc[a][2] = fmaf(s.x, w0.z, acc[a][2]);
                        acc[a][3] = fmaf(s.x, w0.w, acc[a][3]);
                        acc[a][0] = fmaf(s.y, w1.x, acc[a][0]);
                        acc[a][1] = fmaf(s.y, w1.y, acc[a][1]);
                        acc[a][2] = fmaf(s.y, w1.z, acc[a][2]);
                        acc[a][3] = fmaf(s.y, w1.w, acc[a][3]);
                        acc[a][0] = fmaf(s.z, w2.x, acc[a][0]);
                        acc[a][1] = fmaf(s.z, w2.y, acc[a][1]);
                        acc[a][2] = fmaf(s.z, w2.z, acc[a][2]);
                        acc[a][3] = fmaf(s.z, w2.w, acc[a][3]);
                        acc[a][0] = fmaf(s.w, w3.x, acc[a][0]);
                        acc[a][1] = fmaf(s.w, w3.y, acc[a][1]);
                        acc[a][2] = fmaf(s.w, w3.z, acc[a][2]);
                        acc[a][3] = fmaf(s.w, w3.w, acc[a][3]);
                    }
                }
            }
            __syncthreads();
        }
    }

    if (ty < 16) {
        const int f0 = tx * 4;
        float bv[4];
#pragma unroll
        for (int b = 0; b < 4; ++b)
            bv[b] = (bias && (f0 + b) < F) ? bias[(size_t)k * F + f0 + b] : 0.0f;
#pragma unroll
        for (int a = 0; a < 8; ++a) {
            int n = n0 + ty + 16 * a;
            if (n >= N) continue;
            float v[4];
#pragma unroll
            for (int b = 0; b < 4; ++b) {
                float xv = acc[a][b] + bv[b];
                if (relu) xv = fmaxf(xv, 0.0f);
                v[b] = xv;
            }
            if (outF)
                *(float4*)&outF[((size_t)k * N + n) * FW + f0] = make_float4(v[0], v[1], v[2], v[3]);
            if (outH) {
                uint2 uu = make_uint2(pack2(v[0], v[1]), pack2(v[2], v[3]));
                *(uint2*)&outH[((size_t)n * 2 + k) * FW + f0] = uu;
            }
        }
    }
}

// ==================== CSR gather (bf16 payload) ====================
// one 64-lane wave per node; lane -> (k, feature-pair). msg: uint [s][2][PAIRS].
// pre != null: out = bf16(relu(pre + agg));  pre == null: out = bf16(agg).
template<int PAIRS>
__global__ __launch_bounds__(256)
void gather(const int* __restrict__ rowstart, const int* __restrict__ srcidx,
            const float* __restrict__ wgt, const uint_t* __restrict__ msg,
            const float* __restrict__ pre, uint_t* __restrict__ outH, int FW, int N) {
    int gt = blockIdx.x * 256 + threadIdx.x;
    int n = gt >> 6, lane = gt & 63;
    if (n >= N) return;
    int k, pair;
    if (PAIRS == 32) { k = lane >> 5; pair = lane & 31; }
    else { k = lane / PAIRS; pair = lane - k * PAIRS; }
    if (k >= 2) return;
    int beg = rowstart[n], end = rowstart[n + 1];
    float ax = 0.0f, ay = 0.0f;
    int e = beg;
    for (; e + 1 < end; e += 2) {
        int s0 = srcidx[e], s1 = srcidx[e + 1];
        float w0 = wgt[e], w1 = wgt[e + 1];
        uint_t u0 = msg[((size_t)s0 * 2 + k) * PAIRS + pair];
        uint_t u1 = msg[((size_t)s1 * 2 + k) * PAIRS + pair];
        ax = fmaf(bf2f((ushort_t)u0), w0, ax);
        ay = fmaf(bf2f((ushort_t)(u0 >> 16)), w0, ay);
        ax = fmaf(bf2f((ushort_t)u1), w1, ax);
        ay = fmaf(bf2f((ushort_t)(u1 >> 16)), w1, ay);
    }
    if (e < end) {
        int s0 = srcidx[e];
        float w0 = wgt[e];
        uint_t u0 = msg[((size_t)s0 * 2 + k) * PAIRS + pair];
        ax = fmaf(bf2f((ushort_t)u0), w0, ax);
        ay = fmaf(bf2f((ushort_t)(u0 >> 16)), w0, ay);
    }
    size_t oidx = ((size_t)n * 2 + k) * PAIRS + pair;
    if (pre) {
        const float* p = &pre[((size_t)k * N + n) * FW + 2 * pair];
        outH[oidx] = pack2(fmaxf(p[0] + ax, 0.0f), fmaxf(p[1] + ay, 0.0f));
    } else {
        outH[oidx] = pack2(ax, ay);
    }
}

// out[n][c] = log_softmax_c( 0.5*(src[0][n][c] + src[1][n][c]) ), src stride FW
__global__ void logsoftmax_kernel(const float* __restrict__ src, float* __restrict__ out,
                                  int N, int C, int FW) {
    int n = blockIdx.x * blockDim.x + threadIdx.x;
    if (n >= N) return;
    const float* a = src + (size_t)n * FW;
    const float* b = src + (size_t)N * FW + (size_t)n * FW;
    float v[48];
    float mx = -1e30f;
    for (int c = 0; c < C; ++c) {
        float t = 0.5f * (a[c] + b[c]);
        v[c] = t;
        mx = fmaxf(mx, t);
    }
    float s = 0.0f;
    for (int c = 0; c < C; ++c) s += expf(v[c] - mx);
    float ls = logf(s);
    for (int c = 0; c < C; ++c) out[(size_t)n * C + c] = v[c] - mx - ls;
}

extern "C" void kernel_launch(void* const* d_in, const int* in_sizes, int n_in,
                              void* d_out, int out_size, void* d_ws, size_t ws_size,
                              hipStream_t stream) {
    const float* x       = (const float*)d_in[0];
    const int*   ei      = (const int*)  d_in[1];
    const float* w1_init = (const float*)d_in[2];
    const float* w1      = (const float*)d_in[3];
    const float* w1_root = (const float*)d_in[4];
    const float* b1      = (const float*)d_in[5];
    const float* w2_init = (const float*)d_in[6];
    const float* w2      = (const float*)d_in[7];
    const float* w2_root = (const float*)d_in[8];
    const float* b2      = (const float*)d_in[9];

    const int Fin1 = 128, F1 = 64, F2 = 41;
    int N = in_sizes[0] / Fin1;          // 100000
    int E = in_sizes[1] / 2;             // 1600000
    const int* row = ei;
    const int* col = ei + E;

    char* ws = (char*)d_ws;
    size_t off = 0;
    auto carve = [&](size_t bytes) -> void* {
        void* p = ws + off;
        off += (bytes + 255) & ~(size_t)255;
        return p;
    };
    int nblkN = (N + TPB - 1) / TPB;
    int*      cnt      = (int*)     carve((size_t)N * 4);
    int*      incl     = (int*)     carve((size_t)N * 4);
    int*      rowstart = (int*)     carve((size_t)(N + 1) * 4);
    int*      cursor   = (int*)     carve((size_t)N * 4);
    int*      bsum     = (int*)     carve((size_t)nblkN * 4);
    float*    dinv     = (float*)   carve((size_t)N * 4);
    int*      srcidx   = (int*)     carve((size_t)E * 4);
    float*    wgt      = (float*)   carve((size_t)E * 4);
    ushort_t* xh       = (ushort_t*)carve((size_t)N * 128 * 2);      // bf16 x
    ushort_t* hh       = (ushort_t*)carve((size_t)N * 64 * 2);       // bf16 h
    ushort_t* b16A     = (ushort_t*)carve((size_t)N * 2 * 64 * 2);   // P / agg
    ushort_t* b16B     = (ushort_t*)carve((size_t)N * 2 * 64 * 2);   // out_t
    float*    pre      = (float*)   carve((size_t)2 * N * 64 * 4);   // root pre-activation
    float*    outF     = (float*)   carve((size_t)2 * N * 64 * 4);   // t=1 output f32

    // ---- CSR + norm ----
    hipMemsetAsync(cnt, 0, (size_t)N * 4, stream);
    count_kernel<<<(E + TPB - 1) / TPB, TPB, 0, stream>>>(col, cnt, E);
    dinv_kernel <<<nblkN, TPB, 0, stream>>>(cnt, dinv, N);
    scan_block  <<<nblkN, TPB, 0, stream>>>(cnt, incl, bsum, N);
    scan_bsums  <<<1, 1, 0, stream>>>(bsum, nblkN);
    finalize_csr<<<nblkN, TPB, 0, stream>>>(incl, bsum, cnt, rowstart, cursor, N);
    fill_csr    <<<(E + TPB - 1) / TPB, TPB, 0, stream>>>(row, col, dinv, cursor, srcidx, wgt, E);

    // ---- x -> bf16 ----
    int nx = N * 128;
    cvt_kernel<<<(nx + TPB - 1) / TPB, TPB, 0, stream>>>(x, xh, nx);

    dim3 gg((N + 127) / 128, 2);
    int ggb = (N * 64 + TPB - 1) / TPB;

    // ---- layer 1 (128 -> 64), FW=64, PAIRS=32 ----
    // P0 = x @ init_w  (bf16, gather layout)
    gemm2<64><<<gg, TPB, 0, stream>>>(nullptr, nullptr, 0, 0, xh, w1_init, 128,
                                      nullptr, 64, 0, N, nullptr, b16A);
    // pre0 = x @ root0 + b0  (f32)
    gemm2<64><<<gg, TPB, 0, stream>>>(nullptr, nullptr, 0, 0, xh, w1_root, 128,
                                      b1, 64, 0, N, pre, nullptr);
    // out1 = relu(pre0 + A@P0)  (bf16)
    gather<32><<<ggb, TPB, 0, stream>>>(rowstart, srcidx, wgt, (const uint_t*)b16A,
                                        pre, (uint_t*)b16B, 64, N);
    // agg1 = A@out1  (bf16)
    gather<32><<<ggb, TPB, 0, stream>>>(rowstart, srcidx, wgt, (const uint_t*)b16B,
                                        nullptr, (uint_t*)b16A, 64, N);
    // out2 = relu(agg1 @ w1 + x @ root1 + b1[1])  (f32)
    gemm2<64><<<gg, TPB, 0, stream>>>(b16A, w1, 64, 64, xh, w1_root + (size_t)2 * 128 * 64, 128,
                                      b1 + 2 * 64, 64, 1, N, outF, nullptr);
    // h = mean_k(out2) -> bf16
    int nf1 = N * 64;
    mean_cvt_kernel<<<(nf1 + TPB - 1) / TPB, TPB, 0, stream>>>(outF, hh, nf1);

    // ---- layer 2 (64 -> 41), FW=48, PAIRS=24 ----
    gemm2<48><<<gg, TPB, 0, stream>>>(nullptr, nullptr, 0, 0, hh, w2_init, 64,
                                      nullptr, 41, 0, N, nullptr, b16A);
    gemm2<48><<<gg, TPB, 0, stream>>>(nullptr, nullptr, 0, 0, hh, w2_root, 64,
                                      b2, 41, 0, N, pre, nullptr);
    gather<24><<<ggb, TPB, 0, stream>>>(rowstart, srcidx, wgt, (const uint_t*)b16A,
                                        pre, (uint_t*)b16B, 48, N);
    gather<24><<<ggb, TPB, 0, stream>>>(rowstart, srcidx, wgt, (const uint_t*)b16B,
                                        nullptr, (uint_t*)b16A, 48, N);
    gemm2<48><<<gg, TPB, 0, stream>>>(b16A, w2, 41, 48, hh, w2_root + (size_t)2 * 64 * 41, 64,
                                      b2 + 2 * 41, 41, 1, N, outF, nullptr);

    logsoftmax_kernel<<<(N + TPB - 1) / TPB, TPB, 0, stream>>>(outF, (float*)d_out, N, 41, 48);
}

// Round 4
// 903.434 us; speedup vs baseline: 5.4854x; 1.6332x over previous
//
#include <hip/hip_runtime.h>
#include <math.h>

#define TPB 256
typedef unsigned short ushort_t;
typedef unsigned int uint_t;
typedef __attribute__((ext_vector_type(8))) short bf16x8;
typedef __attribute__((ext_vector_type(4))) float f32x4;

__device__ __forceinline__ float bf2f(ushort_t h) {
    return __uint_as_float(((uint_t)h) << 16);
}
__device__ __forceinline__ ushort_t f2bf(float f) {
    uint_t u = __float_as_uint(f);
    u += 0x7fff + ((u >> 16) & 1);
    return (ushort_t)(u >> 16);
}
__device__ __forceinline__ uint_t pack2(float x, float y) {
    return (uint_t)f2bf(x) | ((uint_t)f2bf(y) << 16);
}

// ==================== CSR build + GCN norm ====================
__global__ void count_kernel(const int* __restrict__ col, int* __restrict__ cnt, int E) {
    int e = blockIdx.x * blockDim.x + threadIdx.x;
    if (e < E) atomicAdd(&cnt[col[e]], 1);
}

__global__ void dinv_kernel(const int* __restrict__ cnt, float* __restrict__ dinv, int n) {
    int i = blockIdx.x * blockDim.x + threadIdx.x;
    if (i < n) {
        int d = cnt[i];
        dinv[i] = (d > 0) ? rsqrtf((float)d) : 0.0f;
    }
}

__global__ void scan_block(const int* __restrict__ cnt, int* __restrict__ incl,
                           int* __restrict__ bsum, int N) {
    __shared__ int s[TPB];
    int i = blockIdx.x * TPB + threadIdx.x;
    s[threadIdx.x] = (i < N) ? cnt[i] : 0;
    __syncthreads();
    for (int d = 1; d < TPB; d <<= 1) {
        int t = (threadIdx.x >= d) ? s[threadIdx.x - d] : 0;
        __syncthreads();
        s[threadIdx.x] += t;
        __syncthreads();
    }
    if (i < N) incl[i] = s[threadIdx.x];
    if (threadIdx.x == TPB - 1) bsum[blockIdx.x] = s[TPB - 1];
}

__global__ void scan_bsums(int* __restrict__ bsum, int nb) {
    int acc = 0;
    for (int b = 0; b < nb; ++b) { int v = bsum[b]; bsum[b] = acc; acc += v; }
}

__global__ void finalize_csr(const int* __restrict__ incl, const int* __restrict__ bsum,
                             const int* __restrict__ cnt, int* __restrict__ rowstart,
                             int* __restrict__ cursor, int N) {
    int i = blockIdx.x * TPB + threadIdx.x;
    if (i < N) {
        int v = incl[i] + bsum[blockIdx.x];
        rowstart[i + 1] = v;
        cursor[i] = v - cnt[i];
    }
    if (i == 0) rowstart[0] = 0;
}

__global__ void fill_csr(const int* __restrict__ row, const int* __restrict__ col,
                         const float* __restrict__ dinv, int* __restrict__ cursor,
                         int* __restrict__ srcidx, float* __restrict__ wgt, int E) {
    int e = blockIdx.x * blockDim.x + threadIdx.x;
    if (e < E) {
        int c = col[e], r = row[e];
        int p = atomicAdd(&cursor[c], 1);
        srcidx[p] = r;
        wgt[p] = dinv[r] * dinv[c];
    }
}

// ==================== conversion / mean ====================
__global__ void cvt_kernel(const float* __restrict__ src, ushort_t* __restrict__ dst, int n) {
    int i = blockIdx.x * blockDim.x + threadIdx.x;
    if (i < n) dst[i] = f2bf(src[i]);
}

__global__ void mean_cvt_kernel(const float* __restrict__ srcF, ushort_t* __restrict__ hh, int NF) {
    int i = blockIdx.x * blockDim.x + threadIdx.x;
    if (i < NF) hh[i] = f2bf(0.5f * (srcF[i] + srcF[(size_t)NF + i]));
}

// ==================== MFMA concat-K GEMM ====================
// acc[k][n][0:F] = s1[n,k,:Fi1] @ W1[k] + s2[n,:Fi2] @ W2[k] (+bias[k]) (opt relu)
// s1 layout: [n][2][s1s] bf16 (per-k rows); s2 layout: [n][s2s] bf16 (shared over k).
// Block: 256 thr = 4 waves; tile 128 nodes x FW=CT*16 cols; blockIdx.y = k.
// Weights (f32) are bf16-converted + swizzled to MFMA B-fragment order in LDS.
template<int CT>
__global__ __launch_bounds__(256)
void gemm_mfma(const ushort_t* __restrict__ s1, int s1s, const float* __restrict__ W1, int Fi1,
               const ushort_t* __restrict__ s2, int s2s, const float* __restrict__ W2, int Fi2,
               const float* __restrict__ bias, int F, int relu, int N,
               float* __restrict__ outF, ushort_t* __restrict__ outH) {
    constexpr int FW = CT * 16;
    __shared__ short sB[6 * CT * 512];   // up to 6 k-chunks of B fragments
    const int kblk = blockIdx.y;
    const int n0 = blockIdx.x * 128;
    const int t = threadIdx.x;
    const int w = t >> 6;
    const int lane = t & 63;
    const int quad = lane >> 4;
    const int lr = lane & 15;

    const int CH1 = s1 ? ((Fi1 + 31) >> 5) : 0;
    const int CH2 = s2 ? ((Fi2 + 31) >> 5) : 0;
    const int CH = CH1 + CH2;

    // ---- stage B fragments (bf16, fragment-ordered) ----
    for (int idx = t; idx < CH * CT * 512; idx += 256) {
        int j  = idx & 7;
        int ln = (idx >> 3) & 63;
        int ct = (idx >> 9) % CT;
        int c  = idx / (CT * 512);
        int q  = ln >> 4;
        int col = ct * 16 + (ln & 15);
        int cc, Fi; const float* W;
        if (c < CH1) { cc = c; Fi = Fi1; W = W1; }
        else         { cc = c - CH1; Fi = Fi2; W = W2; }
        int kk = cc * 32 + q * 8 + j;
        float v = (kk < Fi && col < F) ? W[(size_t)kblk * Fi * F + (size_t)kk * F + col] : 0.0f;
        sB[idx] = (short)f2bf(v);
    }
    __syncthreads();

    // ---- K loop ----
    f32x4 acc[2][CT];
#pragma unroll
    for (int rt = 0; rt < 2; ++rt)
#pragma unroll
        for (int ct = 0; ct < CT; ++ct) acc[rt][ct] = (f32x4){0.f, 0.f, 0.f, 0.f};

    int r0 = n0 + w * 32 + lr;
    int m0 = r0 < N ? r0 : N - 1;
    int m1 = (r0 + 16) < N ? (r0 + 16) : N - 1;

    for (int c = 0; c < CH; ++c) {
        bf16x8 a0, a1;
        if (c < CH1) {
            int off = c * 32 + quad * 8;
            a0 = *(const bf16x8*)&s1[((size_t)m0 * 2 + kblk) * s1s + off];
            a1 = *(const bf16x8*)&s1[((size_t)m1 * 2 + kblk) * s1s + off];
        } else {
            int off = (c - CH1) * 32 + quad * 8;
            a0 = *(const bf16x8*)&s2[(size_t)m0 * s2s + off];
            a1 = *(const bf16x8*)&s2[(size_t)m1 * s2s + off];
        }
#pragma unroll
        for (int ct = 0; ct < CT; ++ct) {
            bf16x8 b = *(const bf16x8*)&sB[(c * CT + ct) * 512 + lane * 8];
            acc[0][ct] = __builtin_amdgcn_mfma_f32_16x16x32_bf16(a0, b, acc[0][ct], 0, 0, 0);
            acc[1][ct] = __builtin_amdgcn_mfma_f32_16x16x32_bf16(a1, b, acc[1][ct], 0, 0, 0);
        }
    }

    // ---- epilogue: D row = quad*4+i, col = ct*16+lr ----
    float bv[CT];
#pragma unroll
    for (int ct = 0; ct < CT; ++ct) {
        int col = ct * 16 + lr;
        bv[ct] = (bias && col < F) ? bias[(size_t)kblk * F + col] : 0.0f;
    }
#pragma unroll
    for (int rt = 0; rt < 2; ++rt) {
#pragma unroll
        for (int i = 0; i < 4; ++i) {
            int n = n0 + w * 32 + rt * 16 + quad * 4 + i;
            if (n >= N) continue;
#pragma unroll
            for (int ct = 0; ct < CT; ++ct) {
                int col = ct * 16 + lr;
                float v = acc[rt][ct][i] + bv[ct];
                if (relu) v = fmaxf(v, 0.0f);
                if (outF) outF[((size_t)kblk * N + n) * FW + col] = v;
                if (outH) outH[((size_t)n * 2 + kblk) * FW + col] = f2bf(v);
            }
        }
    }
}

// ==================== CSR gather (bf16 payload) ====================
template<int PAIRS>
__global__ __launch_bounds__(256)
void gather(const int* __restrict__ rowstart, const int* __restrict__ srcidx,
            const float* __restrict__ wgt, const uint_t* __restrict__ msg,
            const float* __restrict__ pre, uint_t* __restrict__ outH, int FW, int N) {
    int gt = blockIdx.x * 256 + threadIdx.x;
    int n = gt >> 6, lane = gt & 63;
    if (n >= N) return;
    int k, pair;
    if (PAIRS == 32) { k = lane >> 5; pair = lane & 31; }
    else { k = lane / PAIRS; pair = lane - k * PAIRS; }
    if (k >= 2) return;
    int beg = rowstart[n], end = rowstart[n + 1];
    float ax = 0.0f, ay = 0.0f;
    int e = beg;
    for (; e + 3 < end; e += 4) {
        int s0 = srcidx[e], s1 = srcidx[e + 1], s2 = srcidx[e + 2], s3 = srcidx[e + 3];
        float w0 = wgt[e], w1 = wgt[e + 1], w2 = wgt[e + 2], w3 = wgt[e + 3];
        uint_t u0 = msg[((size_t)s0 * 2 + k) * PAIRS + pair];
        uint_t u1 = msg[((size_t)s1 * 2 + k) * PAIRS + pair];
        uint_t u2 = msg[((size_t)s2 * 2 + k) * PAIRS + pair];
        uint_t u3 = msg[((size_t)s3 * 2 + k) * PAIRS + pair];
        ax = fmaf(bf2f((ushort_t)u0), w0, ax);
        ay = fmaf(bf2f((ushort_t)(u0 >> 16)), w0, ay);
        ax = fmaf(bf2f((ushort_t)u1), w1, ax);
        ay = fmaf(bf2f((ushort_t)(u1 >> 16)), w1, ay);
        ax = fmaf(bf2f((ushort_t)u2), w2, ax);
        ay = fmaf(bf2f((ushort_t)(u2 >> 16)), w2, ay);
        ax = fmaf(bf2f((ushort_t)u3), w3, ax);
        ay = fmaf(bf2f((ushort_t)(u3 >> 16)), w3, ay);
    }
    for (; e < end; ++e) {
        int s0 = srcidx[e];
        float w0 = wgt[e];
        uint_t u0 = msg[((size_t)s0 * 2 + k) * PAIRS + pair];
        ax = fmaf(bf2f((ushort_t)u0), w0, ax);
        ay = fmaf(bf2f((ushort_t)(u0 >> 16)), w0, ay);
    }
    size_t oidx = ((size_t)n * 2 + k) * PAIRS + pair;
    if (pre) {
        const float* p = &pre[((size_t)k * N + n) * FW + 2 * pair];
        outH[oidx] = pack2(fmaxf(p[0] + ax, 0.0f), fmaxf(p[1] + ay, 0.0f));
    } else {
        outH[oidx] = pack2(ax, ay);
    }
}

// out[n][c] = log_softmax_c( 0.5*(src[0][n][c] + src[1][n][c]) ), src stride FW
__global__ void logsoftmax_kernel(const float* __restrict__ src, float* __restrict__ out,
                                  int N, int C, int FW) {
    int n = blockIdx.x * blockDim.x + threadIdx.x;
    if (n >= N) return;
    const float* a = src + (size_t)n * FW;
    const float* b = src + (size_t)N * FW + (size_t)n * FW;
    float v[48];
    float mx = -1e30f;
    for (int c = 0; c < C; ++c) {
        float t = 0.5f * (a[c] + b[c]);
        v[c] = t;
        mx = fmaxf(mx, t);
    }
    float s = 0.0f;
    for (int c = 0; c < C; ++c) s += expf(v[c] - mx);
    float ls = logf(s);
    for (int c = 0; c < C; ++c) out[(size_t)n * C + c] = v[c] - mx - ls;
}

extern "C" void kernel_launch(void* const* d_in, const int* in_sizes, int n_in,
                              void* d_out, int out_size, void* d_ws, size_t ws_size,
                              hipStream_t stream) {
    const float* x       = (const float*)d_in[0];
    const int*   ei      = (const int*)  d_in[1];
    const float* w1_init = (const float*)d_in[2];
    const float* w1      = (const float*)d_in[3];
    const float* w1_root = (const float*)d_in[4];
    const float* b1      = (const float*)d_in[5];
    const float* w2_init = (const float*)d_in[6];
    const float* w2      = (const float*)d_in[7];
    const float* w2_root = (const float*)d_in[8];
    const float* b2      = (const float*)d_in[9];

    const int Fin1 = 128;
    int N = in_sizes[0] / Fin1;          // 100000
    int E = in_sizes[1] / 2;             // 1600000
    const int* row = ei;
    const int* col = ei + E;

    char* ws = (char*)d_ws;
    size_t off = 0;
    auto carve = [&](size_t bytes) -> void* {
        void* p = ws + off;
        off += (bytes + 255) & ~(size_t)255;
        return p;
    };
    int nblkN = (N + TPB - 1) / TPB;
    int*      cnt      = (int*)     carve((size_t)N * 4);
    int*      incl     = (int*)     carve((size_t)N * 4);
    int*      rowstart = (int*)     carve((size_t)(N + 1) * 4);
    int*      cursor   = (int*)     carve((size_t)N * 4);
    int*      bsum     = (int*)     carve((size_t)nblkN * 4);
    float*    dinv     = (float*)   carve((size_t)N * 4);
    int*      srcidx   = (int*)     carve((size_t)E * 4);
    float*    wgt      = (float*)   carve((size_t)E * 4);
    ushort_t* xh       = (ushort_t*)carve((size_t)N * 128 * 2);      // bf16 x
    ushort_t* hh       = (ushort_t*)carve((size_t)N * 64 * 2);       // bf16 h
    ushort_t* b16A     = (ushort_t*)carve((size_t)N * 2 * 64 * 2);   // P / agg
    ushort_t* b16B     = (ushort_t*)carve((size_t)N * 2 * 64 * 2);   // out_t
    float*    pre      = (float*)   carve((size_t)2 * N * 64 * 4);   // root pre-activation
    float*    outF     = (float*)   carve((size_t)2 * N * 64 * 4);   // t=1 output f32

    // ---- CSR + norm ----
    hipMemsetAsync(cnt, 0, (size_t)N * 4, stream);
    count_kernel<<<(E + TPB - 1) / TPB, TPB, 0, stream>>>(col, cnt, E);
    dinv_kernel <<<nblkN, TPB, 0, stream>>>(cnt, dinv, N);
    scan_block  <<<nblkN, TPB, 0, stream>>>(cnt, incl, bsum, N);
    scan_bsums  <<<1, 1, 0, stream>>>(bsum, nblkN);
    finalize_csr<<<nblkN, TPB, 0, stream>>>(incl, bsum, cnt, rowstart, cursor, N);
    fill_csr    <<<(E + TPB - 1) / TPB, TPB, 0, stream>>>(row, col, dinv, cursor, srcidx, wgt, E);

    // ---- x -> bf16 ----
    int nx = N * 128;
    cvt_kernel<<<(nx + TPB - 1) / TPB, TPB, 0, stream>>>(x, xh, nx);

    dim3 gg((N + 127) / 128, 2);
    int ggb = (N * 64 + TPB - 1) / TPB;

    // ---- layer 1 (128 -> 64), FW=64, PAIRS=32 ----
    // P0 = x @ init_w (bf16, gather layout)
    gemm_mfma<4><<<gg, TPB, 0, stream>>>(nullptr, 0, nullptr, 0, xh, 128, w1_init, 128,
                                         nullptr, 64, 0, N, nullptr, b16A);
    // pre0 = x @ root0 + b0 (f32)
    gemm_mfma<4><<<gg, TPB, 0, stream>>>(nullptr, 0, nullptr, 0, xh, 128, w1_root, 128,
                                         b1, 64, 0, N, pre, nullptr);
    // out1 = relu(pre0 + A@P0) (bf16)
    gather<32><<<ggb, TPB, 0, stream>>>(rowstart, srcidx, wgt, (const uint_t*)b16A,
                                        pre, (uint_t*)b16B, 64, N);
    // agg1 = A@out1 (bf16)
    gather<32><<<ggb, TPB, 0, stream>>>(rowstart, srcidx, wgt, (const uint_t*)b16B,
                                        nullptr, (uint_t*)b16A, 64, N);
    // out2 = relu(agg1 @ w1 + x @ root1 + b1[1]) (f32)
    gemm_mfma<4><<<gg, TPB, 0, stream>>>(b16A, 64, w1, 64, xh, 128,
                                         w1_root + (size_t)2 * 128 * 64, 128,
                                         b1 + 2 * 64, 64, 1, N, outF, nullptr);
    // h = mean_k(out2) -> bf16
    int nf1 = N * 64;
    mean_cvt_kernel<<<(nf1 + TPB - 1) / TPB, TPB, 0, stream>>>(outF, hh, nf1);

    // ---- layer 2 (64 -> 41), FW=48, PAIRS=24 ----
    gemm_mfma<3><<<gg, TPB, 0, stream>>>(nullptr, 0, nullptr, 0, hh, 64, w2_init, 64,
                                         nullptr, 41, 0, N, nullptr, b16A);
    gemm_mfma<3><<<gg, TPB, 0, stream>>>(nullptr, 0, nullptr, 0, hh, 64, w2_root, 64,
                                         b2, 41, 0, N, pre, nullptr);
    gather<24><<<ggb, TPB, 0, stream>>>(rowstart, srcidx, wgt, (const uint_t*)b16A,
                                        pre, (uint_t*)b16B, 48, N);
    gather<24><<<ggb, TPB, 0, stream>>>(rowstart, srcidx, wgt, (const uint_t*)b16B,
                                        nullptr, (uint_t*)b16A, 48, N);
    gemm_mfma<3><<<gg, TPB, 0, stream>>>(b16A, 48, w2, 41, hh, 64,
                                         w2_root + (size_t)2 * 64 * 41, 64,
                                         b2 + 2 * 41, 41, 1, N, outF, nullptr);

    logsoftmax_kernel<<<(N + TPB - 1) / TPB, TPB, 0, stream>>>(outF, (float*)d_out, N, 41, 48);
}

// Round 5
// 881.305 us; speedup vs baseline: 5.6231x; 1.0251x over previous
//
#include <hip/hip_runtime.h>
#include <math.h>

#define TPB 256
typedef unsigned short ushort_t;
typedef unsigned int uint_t;
typedef __attribute__((ext_vector_type(8))) short bf16x8;
typedef __attribute__((ext_vector_type(4))) float f32x4;

__device__ __forceinline__ float bf2f(ushort_t h) {
    return __uint_as_float(((uint_t)h) << 16);
}
__device__ __forceinline__ ushort_t f2bf(float f) {
    uint_t u = __float_as_uint(f);
    u += 0x7fff + ((u >> 16) & 1);
    return (ushort_t)(u >> 16);
}
__device__ __forceinline__ uint_t pack2(float x, float y) {
    return (uint_t)f2bf(x) | ((uint_t)f2bf(y) << 16);
}

// ==================== CSR build + GCN norm ====================
__global__ void count_kernel(const int* __restrict__ col, int* __restrict__ cnt, int E) {
    int e = blockIdx.x * blockDim.x + threadIdx.x;
    if (e < E) atomicAdd(&cnt[col[e]], 1);
}

__global__ void dinv_kernel(const int* __restrict__ cnt, float* __restrict__ dinv, int n) {
    int i = blockIdx.x * blockDim.x + threadIdx.x;
    if (i < n) {
        int d = cnt[i];
        dinv[i] = (d > 0) ? rsqrtf((float)d) : 0.0f;
    }
}

__global__ void scan_block(const int* __restrict__ cnt, int* __restrict__ incl,
                           int* __restrict__ bsum, int N) {
    __shared__ int s[TPB];
    int i = blockIdx.x * TPB + threadIdx.x;
    s[threadIdx.x] = (i < N) ? cnt[i] : 0;
    __syncthreads();
    for (int d = 1; d < TPB; d <<= 1) {
        int t = (threadIdx.x >= d) ? s[threadIdx.x - d] : 0;
        __syncthreads();
        s[threadIdx.x] += t;
        __syncthreads();
    }
    if (i < N) incl[i] = s[threadIdx.x];
    if (threadIdx.x == TPB - 1) bsum[blockIdx.x] = s[TPB - 1];
}

// one-block scan over <=512 block sums (exclusive, in place)
__global__ void scan_bsums(int* __restrict__ bsum, int nb) {
    __shared__ int s[512];
    int t = threadIdx.x;
    int v = (t < nb) ? bsum[t] : 0;
    s[t] = v;
    __syncthreads();
    for (int d = 1; d < 512; d <<= 1) {
        int u = (t >= d) ? s[t - d] : 0;
        __syncthreads();
        s[t] += u;
        __syncthreads();
    }
    if (t < nb) bsum[t] = s[t] - v;
}

__global__ void finalize_csr(const int* __restrict__ incl, const int* __restrict__ bsum,
                             const int* __restrict__ cnt, int* __restrict__ rowstart,
                             int* __restrict__ cursor, int N) {
    int i = blockIdx.x * TPB + threadIdx.x;
    if (i < N) {
        int v = incl[i] + bsum[blockIdx.x];
        rowstart[i + 1] = v;
        cursor[i] = v - cnt[i];
    }
    if (i == 0) rowstart[0] = 0;
}

// writes ONLY srcidx (one scattered 4B store per edge); weights recomputed in gather
__global__ void fill_csr(const int* __restrict__ row, const int* __restrict__ col,
                         int* __restrict__ cursor, int* __restrict__ srcidx, int E) {
    int e = blockIdx.x * blockDim.x + threadIdx.x;
    if (e < E) {
        int c = col[e];
        int p = atomicAdd(&cursor[c], 1);
        srcidx[p] = row[e];
    }
}

// ==================== conversion / mean (vectorized) ====================
__global__ void cvt4_kernel(const float4* __restrict__ src, uint2* __restrict__ dst, int n4) {
    int i = blockIdx.x * blockDim.x + threadIdx.x;
    if (i < n4) {
        float4 v = src[i];
        dst[i] = make_uint2(pack2(v.x, v.y), pack2(v.z, v.w));
    }
}

// hh = bf16(0.5*(srcF[i] + srcF[i+NF])), 4-wide
__global__ void mean_cvt4_kernel(const float4* __restrict__ srcF, uint2* __restrict__ hh, int n4) {
    int i = blockIdx.x * blockDim.x + threadIdx.x;
    if (i < n4) {
        float4 a = srcF[i];
        float4 b = srcF[(size_t)n4 + i];
        hh[i] = make_uint2(pack2(0.5f * (a.x + b.x), 0.5f * (a.y + b.y)),
                           pack2(0.5f * (a.z + b.z), 0.5f * (a.w + b.w)));
    }
}

// ==================== MFMA concat-K / split-col GEMM ====================
// acc[k][n][col] = s1[n,k,:] @ W1[k]  (K-concat, optional)
//               + s2[n,:]   @ (col < SPLIT ? W2a[k] : W2b[k][col-SPLIT])
// Output routing: ct < CTA -> outH bf16 gather layout [n][2][SPLIT]
//                 ct >= CTA -> outF f32 [k][N][(CT-CTA)*16], col' = col - CTA*16
// biasA on cols [0,SPLIT) (valid < FA), biasB on cols >= SPLIT (valid < FB).
template<int CT, int MAXCH>
__global__ __launch_bounds__(256)
void gemm_mfma(const ushort_t* __restrict__ s1, int s1s, const float* __restrict__ W1, int Fi1,
               const ushort_t* __restrict__ s2, int s2s,
               const float* __restrict__ W2a, int FA, const float* __restrict__ W2b, int FB,
               int SPLIT, int Fi2,
               const float* __restrict__ biasA, const float* __restrict__ biasB,
               int relu, int N, int CTA,
               float* __restrict__ outF, ushort_t* __restrict__ outH) {
    __shared__ short sB[MAXCH * CT * 512];
    const int kblk = blockIdx.y;
    const int n0 = blockIdx.x * 128;
    const int t = threadIdx.x;
    const int w = t >> 6;
    const int lane = t & 63;
    const int quad = lane >> 4;
    const int lr = lane & 15;

    const int CH1 = s1 ? ((Fi1 + 31) >> 5) : 0;
    const int CH2 = s2 ? ((Fi2 + 31) >> 5) : 0;
    const int CH = CH1 + CH2;

    // ---- stage B fragments (f32 weights -> bf16, fragment order) ----
    for (int idx = t; idx < CH * CT * 512; idx += 256) {
        int j  = idx & 7;
        int ln = (idx >> 3) & 63;
        int ct = (idx >> 9) % CT;
        int c  = idx / (CT * 512);
        int q  = ln >> 4;
        int col = ct * 16 + (ln & 15);
        int kk_local = q * 8 + j;
        float v = 0.0f;
        if (c < CH1) {
            int kk = c * 32 + kk_local;
            if (kk < Fi1 && col < FA)
                v = W1[((size_t)kblk * Fi1 + kk) * FA + col];
        } else {
            int kk = (c - CH1) * 32 + kk_local;
            if (kk < Fi2) {
                if (col < SPLIT) {
                    if (col < FA) v = W2a[((size_t)kblk * Fi2 + kk) * FA + col];
                } else {
                    int c2 = col - SPLIT;
                    if (c2 < FB) v = W2b[((size_t)kblk * Fi2 + kk) * FB + c2];
                }
            }
        }
        sB[idx] = (short)f2bf(v);
    }
    __syncthreads();

    // ---- K loop ----
    f32x4 acc[2][CT];
#pragma unroll
    for (int rt = 0; rt < 2; ++rt)
#pragma unroll
        for (int ct = 0; ct < CT; ++ct) acc[rt][ct] = (f32x4){0.f, 0.f, 0.f, 0.f};

    int r0 = n0 + w * 32 + lr;
    int m0 = r0 < N ? r0 : N - 1;
    int m1 = (r0 + 16) < N ? (r0 + 16) : N - 1;

    for (int c = 0; c < CH; ++c) {
        bf16x8 a0, a1;
        if (c < CH1) {
            int off = c * 32 + quad * 8;
            a0 = *(const bf16x8*)&s1[((size_t)m0 * 2 + kblk) * s1s + off];
            a1 = *(const bf16x8*)&s1[((size_t)m1 * 2 + kblk) * s1s + off];
        } else {
            int off = (c - CH1) * 32 + quad * 8;
            a0 = *(const bf16x8*)&s2[(size_t)m0 * s2s + off];
            a1 = *(const bf16x8*)&s2[(size_t)m1 * s2s + off];
        }
#pragma unroll
        for (int ct = 0; ct < CT; ++ct) {
            bf16x8 b = *(const bf16x8*)&sB[(c * CT + ct) * 512 + lane * 8];
            acc[0][ct] = __builtin_amdgcn_mfma_f32_16x16x32_bf16(a0, b, acc[0][ct], 0, 0, 0);
            acc[1][ct] = __builtin_amdgcn_mfma_f32_16x16x32_bf16(a1, b, acc[1][ct], 0, 0, 0);
        }
    }

    // ---- epilogue: D row = quad*4+i, col = ct*16+lr ----
    const int FWB = (CT - CTA) * 16;
    float bv[CT];
#pragma unroll
    for (int ct = 0; ct < CT; ++ct) {
        int col = ct * 16 + lr;
        float b = 0.0f;
        if (col < SPLIT) {
            if (biasA && col < FA) b = biasA[(size_t)kblk * FA + col];
        } else {
            int c2 = col - SPLIT;
            if (biasB && c2 < FB) b = biasB[(size_t)kblk * FB + c2];
        }
        bv[ct] = b;
    }
#pragma unroll
    for (int rt = 0; rt < 2; ++rt) {
#pragma unroll
        for (int i = 0; i < 4; ++i) {
            int n = n0 + w * 32 + rt * 16 + quad * 4 + i;
            if (n >= N) continue;
#pragma unroll
            for (int ct = 0; ct < CT; ++ct) {
                int col = ct * 16 + lr;
                float v = acc[rt][ct][i] + bv[ct];
                if (relu) v = fmaxf(v, 0.0f);
                if (ct < CTA) {
                    outH[((size_t)n * 2 + kblk) * SPLIT + col] = f2bf(v);
                } else {
                    outF[((size_t)kblk * N + n) * FWB + (col - CTA * 16)] = v;
                }
            }
        }
    }
}

// ==================== CSR gather (bf16 payload, weights from dinv) ====================
template<int PAIRS>
__global__ __launch_bounds__(256)
void gather(const int* __restrict__ rowstart, const int* __restrict__ srcidx,
            const float* __restrict__ dinv, const uint_t* __restrict__ msg,
            const float* __restrict__ pre, uint_t* __restrict__ outH, int FW, int N) {
    int gt = blockIdx.x * 256 + threadIdx.x;
    int n = gt >> 6, lane = gt & 63;
    if (n >= N) return;
    int k, pair;
    if (PAIRS == 32) { k = lane >> 5; pair = lane & 31; }
    else { k = lane / PAIRS; pair = lane - k * PAIRS; }
    if (k >= 2) return;
    int beg = rowstart[n], end = rowstart[n + 1];
    float dn = dinv[n];
    float ax = 0.0f, ay = 0.0f;
    int e = beg;
    for (; e + 3 < end; e += 4) {
        int s0 = srcidx[e], s1 = srcidx[e + 1], s2 = srcidx[e + 2], s3 = srcidx[e + 3];
        float w0 = dinv[s0] * dn, w1 = dinv[s1] * dn, w2 = dinv[s2] * dn, w3 = dinv[s3] * dn;
        uint_t u0 = msg[((size_t)s0 * 2 + k) * PAIRS + pair];
        uint_t u1 = msg[((size_t)s1 * 2 + k) * PAIRS + pair];
        uint_t u2 = msg[((size_t)s2 * 2 + k) * PAIRS + pair];
        uint_t u3 = msg[((size_t)s3 * 2 + k) * PAIRS + pair];
        ax = fmaf(bf2f((ushort_t)u0), w0, ax);
        ay = fmaf(bf2f((ushort_t)(u0 >> 16)), w0, ay);
        ax = fmaf(bf2f((ushort_t)u1), w1, ax);
        ay = fmaf(bf2f((ushort_t)(u1 >> 16)), w1, ay);
        ax = fmaf(bf2f((ushort_t)u2), w2, ax);
        ay = fmaf(bf2f((ushort_t)(u2 >> 16)), w2, ay);
        ax = fmaf(bf2f((ushort_t)u3), w3, ax);
        ay = fmaf(bf2f((ushort_t)(u3 >> 16)), w3, ay);
    }
    for (; e < end; ++e) {
        int s0 = srcidx[e];
        float w0 = dinv[s0] * dn;
        uint_t u0 = msg[((size_t)s0 * 2 + k) * PAIRS + pair];
        ax = fmaf(bf2f((ushort_t)u0), w0, ax);
        ay = fmaf(bf2f((ushort_t)(u0 >> 16)), w0, ay);
    }
    size_t oidx = ((size_t)n * 2 + k) * PAIRS + pair;
    if (pre) {
        const float* p = &pre[((size_t)k * N + n) * FW + 2 * pair];
        outH[oidx] = pack2(fmaxf(p[0] + ax, 0.0f), fmaxf(p[1] + ay, 0.0f));
    } else {
        outH[oidx] = pack2(ax, ay);
    }
}

// out[n][c] = log_softmax_c( 0.5*(src[0][n][c] + src[1][n][c]) ), src stride FW
__global__ void logsoftmax_kernel(const float* __restrict__ src, float* __restrict__ out,
                                  int N, int C, int FW) {
    int n = blockIdx.x * blockDim.x + threadIdx.x;
    if (n >= N) return;
    const float* a = src + (size_t)n * FW;
    const float* b = src + (size_t)N * FW + (size_t)n * FW;
    float v[48];
    float mx = -1e30f;
    for (int c = 0; c < C; ++c) {
        float t = 0.5f * (a[c] + b[c]);
        v[c] = t;
        mx = fmaxf(mx, t);
    }
    float s = 0.0f;
    for (int c = 0; c < C; ++c) s += expf(v[c] - mx);
    float ls = logf(s);
    for (int c = 0; c < C; ++c) out[(size_t)n * C + c] = v[c] - mx - ls;
}

extern "C" void kernel_launch(void* const* d_in, const int* in_sizes, int n_in,
                              void* d_out, int out_size, void* d_ws, size_t ws_size,
                              hipStream_t stream) {
    const float* x       = (const float*)d_in[0];
    const int*   ei      = (const int*)  d_in[1];
    const float* w1_init = (const float*)d_in[2];
    const float* w1      = (const float*)d_in[3];
    const float* w1_root = (const float*)d_in[4];
    const float* b1      = (const float*)d_in[5];
    const float* w2_init = (const float*)d_in[6];
    const float* w2      = (const float*)d_in[7];
    const float* w2_root = (const float*)d_in[8];
    const float* b2      = (const float*)d_in[9];

    const int Fin1 = 128;
    int N = in_sizes[0] / Fin1;          // 100000
    int E = in_sizes[1] / 2;             // 1600000
    const int* row = ei;
    const int* col = ei + E;

    char* ws = (char*)d_ws;
    size_t off = 0;
    auto carve = [&](size_t bytes) -> void* {
        void* p = ws + off;
        off += (bytes + 255) & ~(size_t)255;
        return p;
    };
    int nblkN = (N + TPB - 1) / TPB;   // 391 (<=512 for the one-block scan)
    int*      cnt      = (int*)     carve((size_t)N * 4);
    int*      incl     = (int*)     carve((size_t)N * 4);
    int*      rowstart = (int*)     carve((size_t)(N + 1) * 4);
    int*      cursor   = (int*)     carve((size_t)N * 4);
    int*      bsum     = (int*)     carve((size_t)nblkN * 4);
    float*    dinv     = (float*)   carve((size_t)N * 4);
    int*      srcidx   = (int*)     carve((size_t)E * 4);
    ushort_t* xh       = (ushort_t*)carve((size_t)N * 128 * 2);      // bf16 x
    ushort_t* hh       = (ushort_t*)carve((size_t)N * 64 * 2);       // bf16 h
    ushort_t* b16A     = (ushort_t*)carve((size_t)N * 2 * 64 * 2);   // P / agg
    ushort_t* b16B     = (ushort_t*)carve((size_t)N * 2 * 64 * 2);   // out_t
    float*    pre      = (float*)   carve((size_t)2 * N * 64 * 4);   // root pre-activation
    float*    outF     = (float*)   carve((size_t)2 * N * 64 * 4);   // t=1 output f32

    // ---- CSR + norm ----
    hipMemsetAsync(cnt, 0, (size_t)N * 4, stream);
    count_kernel<<<(E + TPB - 1) / TPB, TPB, 0, stream>>>(col, cnt, E);
    dinv_kernel <<<nblkN, TPB, 0, stream>>>(cnt, dinv, N);
    scan_block  <<<nblkN, TPB, 0, stream>>>(cnt, incl, bsum, N);
    scan_bsums  <<<1, 512, 0, stream>>>(bsum, nblkN);
    finalize_csr<<<nblkN, TPB, 0, stream>>>(incl, bsum, cnt, rowstart, cursor, N);
    fill_csr    <<<(E + TPB - 1) / TPB, TPB, 0, stream>>>(row, col, cursor, srcidx, E);

    // ---- x -> bf16 ----
    int nx4 = N * 128 / 4;
    cvt4_kernel<<<(nx4 + TPB - 1) / TPB, TPB, 0, stream>>>((const float4*)x, (uint2*)xh, nx4);

    dim3 gg((N + 127) / 128, 2);
    int ggb = (N * 64 + TPB - 1) / TPB;

    // ---- layer 1 (128 -> 64), SPLIT=64, PAIRS=32 ----
    // fused t=0: cols 0-63 -> P0 (b16A, gather layout); cols 64-127 -> pre = x@root0+b0 (f32)
    gemm_mfma<8, 4><<<gg, TPB, 0, stream>>>(nullptr, 0, nullptr, 0, xh, 128,
                                            w1_init, 64, w1_root, 64, 64, 128,
                                            nullptr, b1, 0, N, 4, pre, b16A);
    // out1 = relu(pre + A@P0) (bf16)
    gather<32><<<ggb, TPB, 0, stream>>>(rowstart, srcidx, dinv, (const uint_t*)b16A,
                                        pre, (uint_t*)b16B, 64, N);
    // agg = A@out1 (bf16)
    gather<32><<<ggb, TPB, 0, stream>>>(rowstart, srcidx, dinv, (const uint_t*)b16B,
                                        nullptr, (uint_t*)b16A, 64, N);
    // out2 = relu(agg@w1 + x@root1 + b1[1]) (f32, width 64)
    gemm_mfma<4, 6><<<gg, TPB, 0, stream>>>(b16A, 64, w1, 64, xh, 128,
                                            w1_root + (size_t)2 * 128 * 64, 64, nullptr, 0, 64, 128,
                                            b1 + 2 * 64, nullptr, 1, N, 0, outF, nullptr);
    // h = mean_k(out2) -> bf16
    int nh4 = N * 64 / 4;
    mean_cvt4_kernel<<<(nh4 + TPB - 1) / TPB, TPB, 0, stream>>>((const float4*)outF, (uint2*)hh, nh4);

    // ---- layer 2 (64 -> 41), SPLIT=48, PAIRS=24 ----
    // fused t=0: cols 0-47 -> P (b16A); cols 48-95 -> pre = h@root0+b0 (f32, stride 48)
    gemm_mfma<6, 2><<<gg, TPB, 0, stream>>>(nullptr, 0, nullptr, 0, hh, 64,
                                            w2_init, 41, w2_root, 41, 48, 64,
                                            nullptr, b2, 0, N, 3, pre, b16A);
    gather<24><<<ggb, TPB, 0, stream>>>(rowstart, srcidx, dinv, (const uint_t*)b16A,
                                        pre, (uint_t*)b16B, 48, N);
    gather<24><<<ggb, TPB, 0, stream>>>(rowstart, srcidx, dinv, (const uint_t*)b16B,
                                        nullptr, (uint_t*)b16A, 48, N);
    // out2 = relu(agg@w2 + h@root1 + b2[1]) (f32, width 48)
    gemm_mfma<3, 4><<<gg, TPB, 0, stream>>>(b16A, 48, w2, 41, hh, 64,
                                            w2_root + (size_t)2 * 64 * 41, 41, nullptr, 0, 48, 64,
                                            b2 + 2 * 41, nullptr, 1, N, 0, outF, nullptr);

    logsoftmax_kernel<<<(N + TPB - 1) / TPB, TPB, 0, stream>>>(outF, (float*)d_out, N, 41, 48);
}

// Round 6
// 629.974 us; speedup vs baseline: 7.8665x; 1.3990x over previous
//
#include <hip/hip_runtime.h>
#include <math.h>

#define TPB 256
typedef unsigned short ushort_t;
typedef unsigned int uint_t;
typedef __attribute__((ext_vector_type(8))) short bf16x8;
typedef __attribute__((ext_vector_type(4))) float f32x4;

__device__ __forceinline__ float bf2f(ushort_t h) {
    return __uint_as_float(((uint_t)h) << 16);
}
__device__ __forceinline__ ushort_t f2bf(float f) {
    uint_t u = __float_as_uint(f);
    u += 0x7fff + ((u >> 16) & 1);
    return (ushort_t)(u >> 16);
}
__device__ __forceinline__ uint_t pack2(float x, float y) {
    return (uint_t)f2bf(x) | ((uint_t)f2bf(y) << 16);
}

// ==================== CSR build + GCN norm ====================
// rank pass: pos[e] = arrival rank of edge e at its destination; cnt ends as degree
__global__ void rank_kernel(const int* __restrict__ col, int* __restrict__ cnt,
                            int* __restrict__ pos, int E) {
    int e = blockIdx.x * blockDim.x + threadIdx.x;
    if (e < E) pos[e] = atomicAdd(&cnt[col[e]], 1);
}

__global__ void dinv_kernel(const int* __restrict__ cnt, float* __restrict__ dinv, int n) {
    int i = blockIdx.x * blockDim.x + threadIdx.x;
    if (i < n) {
        int d = cnt[i];
        dinv[i] = (d > 0) ? rsqrtf((float)d) : 0.0f;
    }
}

__global__ void scan_block(const int* __restrict__ cnt, int* __restrict__ incl,
                           int* __restrict__ bsum, int N) {
    __shared__ int s[TPB];
    int i = blockIdx.x * TPB + threadIdx.x;
    s[threadIdx.x] = (i < N) ? cnt[i] : 0;
    __syncthreads();
    for (int d = 1; d < TPB; d <<= 1) {
        int t = (threadIdx.x >= d) ? s[threadIdx.x - d] : 0;
        __syncthreads();
        s[threadIdx.x] += t;
        __syncthreads();
    }
    if (i < N) incl[i] = s[threadIdx.x];
    if (threadIdx.x == TPB - 1) bsum[blockIdx.x] = s[TPB - 1];
}

__global__ void scan_bsums(int* __restrict__ bsum, int nb) {
    __shared__ int s[512];
    int t = threadIdx.x;
    int v = (t < nb) ? bsum[t] : 0;
    s[t] = v;
    __syncthreads();
    for (int d = 1; d < 512; d <<= 1) {
        int u = (t >= d) ? s[t - d] : 0;
        __syncthreads();
        s[t] += u;
        __syncthreads();
    }
    if (t < nb) bsum[t] = s[t] - v;
}

__global__ void finalize_csr(const int* __restrict__ incl, const int* __restrict__ bsum,
                             int* __restrict__ rowstart, int N) {
    int i = blockIdx.x * TPB + threadIdx.x;
    if (i < N) rowstart[i + 1] = incl[i] + bsum[blockIdx.x];
    if (i == 0) rowstart[0] = 0;
}

// atomic-free fill: position = rowstart[col] + pos[e]
__global__ void fill_csr(const int* __restrict__ row, const int* __restrict__ col,
                         const int* __restrict__ rowstart, const int* __restrict__ pos,
                         int* __restrict__ srcidx, int E) {
    int e = blockIdx.x * blockDim.x + threadIdx.x;
    if (e < E) srcidx[rowstart[col[e]] + pos[e]] = row[e];
}

// ==================== conversion ====================
__global__ void cvt4_kernel(const float4* __restrict__ src, uint2* __restrict__ dst, int n4) {
    int i = blockIdx.x * blockDim.x + threadIdx.x;
    if (i < n4) {
        float4 v = src[i];
        dst[i] = make_uint2(pack2(v.x, v.y), pack2(v.z, v.w));
    }
}

// ==================== weight pre-swizzle (bf16 B-fragment order) ====================
// frag element: dst[region + ((k*CH + c)*CT + ct)*512 + ln*8 + j] holds
//   W[kk = c*32 + (ln>>4)*8 + j][col = ct*16 + (ln&15)]  (0 outside valid range)
// Regions (shorts): A: L1-t0 k2*CH4*CT8  B: L1-t1 k2*CH6*CT4  C: L2-t0 k2*CH2*CT6  D: L2-t1 k2*CH4*CT3
#define SWZ_A 32768
#define SWZ_B 24576
#define SWZ_C 12288
#define SWZ_D 12288
__global__ void swz_all(const float* __restrict__ w1_init, const float* __restrict__ w1,
                        const float* __restrict__ w1_root, const float* __restrict__ w2_init,
                        const float* __restrict__ w2, const float* __restrict__ w2_root,
                        short* __restrict__ dst) {
    int idx = blockIdx.x * blockDim.x + threadIdx.x;
    int region, base, CH, CT;
    if (idx < SWZ_A)                          { region = 0; base = 0; CH = 4; CT = 8; }
    else if (idx < SWZ_A + SWZ_B)             { region = 1; base = SWZ_A; CH = 6; CT = 4; }
    else if (idx < SWZ_A + SWZ_B + SWZ_C)     { region = 2; base = SWZ_A + SWZ_B; CH = 2; CT = 6; }
    else if (idx < SWZ_A + SWZ_B + SWZ_C + SWZ_D)
                                              { region = 3; base = SWZ_A + SWZ_B + SWZ_C; CH = 4; CT = 3; }
    else return;
    int r = idx - base;
    int j = r & 7, ln = (r >> 3) & 63;
    int rest = r >> 9;
    int ct = rest % CT, c = (rest / CT) % CH, k = rest / (CT * CH);
    int col = ct * 16 + (ln & 15);
    int kl = (ln >> 4) * 8 + j;
    float v = 0.0f;
    if (region == 0) {              // L1-t0: x(128) -> [init(64) | root_t0(64)]
        int kk = c * 32 + kl;       // < 128 always
        if (col < 64)       v = w1_init[((size_t)k * 128 + kk) * 64 + col];
        else                v = w1_root[((size_t)(0 * 2 + k) * 128 + kk) * 64 + (col - 64)];
    } else if (region == 1) {       // L1-t1: c<2: agg(64)@w1 ; c>=2: x(128)@root_t1
        if (c < 2) { int kk = c * 32 + kl;        v = w1[((size_t)k * 64 + kk) * 64 + col]; }
        else       { int kk = (c - 2) * 32 + kl;  v = w1_root[((size_t)(2 + k) * 128 + kk) * 64 + col]; }
    } else if (region == 2) {       // L2-t0: h(64) -> [init(41,pad48) | root_t0(41,pad48)]
        int kk = c * 32 + kl;       // < 64
        if (col < 48) { if (col < 41)            v = w2_init[((size_t)k * 64 + kk) * 41 + col]; }
        else          { int c2 = col - 48; if (c2 < 41) v = w2_root[((size_t)(0 * 2 + k) * 64 + kk) * 41 + c2]; }
    } else {                        // L2-t1: c<2: agg(48,rows41)@w2 ; c>=2: h(64)@root_t1
        if (c < 2) { int kk = c * 32 + kl;       if (kk < 41 && col < 41) v = w2[((size_t)k * 41 + kk) * 41 + col]; }
        else       { int kk = (c - 2) * 32 + kl; if (col < 41)            v = w2_root[((size_t)(2 + k) * 64 + kk) * 41 + col]; }
    }
    dst[(size_t)base + r] = (short)f2bf(v);
}

// ==================== t0 GEMM (per-k): s2 @ [Wa | Wb] -> outH bf16 + pre f32 ====================
// ct < CTA -> outH[n][2][CTA*16] (no bias); ct >= CTA -> pre[k][n][(CT-CTA)*16] + biasB
template<int CT, int CTA, int CH>
__global__ __launch_bounds__(256)
void gemm_t0(const ushort_t* __restrict__ s2, int s2s, const short* __restrict__ fragbuf,
             const float* __restrict__ biasB, int FB, int N,
             float* __restrict__ pre, ushort_t* __restrict__ outH) {
    const int k = blockIdx.y;
    const int n0 = blockIdx.x * 128;
    const int t = threadIdx.x;
    const int w = t >> 6, lane = t & 63, quad = lane >> 4, lr = lane & 15;
    const short* fb = fragbuf + (size_t)k * CH * CT * 512;

    int r0 = n0 + w * 32 + lr;
    int m0 = r0 < N ? r0 : N - 1;
    int m1 = (r0 + 16) < N ? (r0 + 16) : N - 1;

    f32x4 acc[2][CT];
#pragma unroll
    for (int rt = 0; rt < 2; ++rt)
#pragma unroll
        for (int ct = 0; ct < CT; ++ct) acc[rt][ct] = (f32x4){0.f, 0.f, 0.f, 0.f};

#pragma unroll
    for (int c = 0; c < CH; ++c) {
        int off = c * 32 + quad * 8;
        bf16x8 a0 = *(const bf16x8*)&s2[(size_t)m0 * s2s + off];
        bf16x8 a1 = *(const bf16x8*)&s2[(size_t)m1 * s2s + off];
#pragma unroll
        for (int ct = 0; ct < CT; ++ct) {
            bf16x8 b = *(const bf16x8*)&fb[((size_t)c * CT + ct) * 512 + lane * 8];
            acc[0][ct] = __builtin_amdgcn_mfma_f32_16x16x32_bf16(a0, b, acc[0][ct], 0, 0, 0);
            acc[1][ct] = __builtin_amdgcn_mfma_f32_16x16x32_bf16(a1, b, acc[1][ct], 0, 0, 0);
        }
    }

    const int FWB = (CT - CTA) * 16;
#pragma unroll
    for (int rt = 0; rt < 2; ++rt) {
#pragma unroll
        for (int i = 0; i < 4; ++i) {
            int n = n0 + w * 32 + rt * 16 + quad * 4 + i;
            if (n >= N) continue;
#pragma unroll
            for (int ct = 0; ct < CT; ++ct) {
                int col = ct * 16 + lr;
                float v = acc[rt][ct][i];
                if (ct < CTA) {
                    outH[((size_t)n * 2 + k) * (CTA * 16) + col] = f2bf(v);
                } else {
                    int c2 = col - CTA * 16;
                    if (c2 < FB) v += biasB[(size_t)k * FB + c2];
                    pre[((size_t)k * N + n) * FWB + c2] = v;
                }
            }
        }
    }
}

// ==================== t1 GEMM layer1, both k fused, epilogue = relu+mean -> hh bf16 ==========
__global__ __launch_bounds__(256)
void gemm_t1_l1(const ushort_t* __restrict__ s1, const ushort_t* __restrict__ xh,
                const short* __restrict__ fragbuf, const float* __restrict__ bias /* b1+2*64 */,
                int N, ushort_t* __restrict__ hh) {
    constexpr int CT = 4, CH = 6;
    const int n0 = blockIdx.x * 128;
    const int t = threadIdx.x;
    const int w = t >> 6, lane = t & 63, quad = lane >> 4, lr = lane & 15;

    int r0 = n0 + w * 32 + lr;
    int m0 = r0 < N ? r0 : N - 1;
    int m1 = (r0 + 16) < N ? (r0 + 16) : N - 1;

    f32x4 acc[2][2][CT];
#pragma unroll
    for (int k = 0; k < 2; ++k)
#pragma unroll
        for (int rt = 0; rt < 2; ++rt)
#pragma unroll
            for (int ct = 0; ct < CT; ++ct) acc[k][rt][ct] = (f32x4){0.f, 0.f, 0.f, 0.f};

#pragma unroll
    for (int c = 0; c < CH; ++c) {
        bf16x8 a0[2], a1[2];
        if (c < 2) {
            int off = c * 32 + quad * 8;
#pragma unroll
            for (int k = 0; k < 2; ++k) {
                a0[k] = *(const bf16x8*)&s1[((size_t)m0 * 2 + k) * 64 + off];
                a1[k] = *(const bf16x8*)&s1[((size_t)m1 * 2 + k) * 64 + off];
            }
        } else {
            int off = (c - 2) * 32 + quad * 8;
            a0[0] = a0[1] = *(const bf16x8*)&xh[(size_t)m0 * 128 + off];
            a1[0] = a1[1] = *(const bf16x8*)&xh[(size_t)m1 * 128 + off];
        }
#pragma unroll
        for (int k = 0; k < 2; ++k) {
            const short* fb = fragbuf + (size_t)k * CH * CT * 512;
#pragma unroll
            for (int ct = 0; ct < CT; ++ct) {
                bf16x8 b = *(const bf16x8*)&fb[((size_t)c * CT + ct) * 512 + lane * 8];
                acc[k][0][ct] = __builtin_amdgcn_mfma_f32_16x16x32_bf16(a0[k], b, acc[k][0][ct], 0, 0, 0);
                acc[k][1][ct] = __builtin_amdgcn_mfma_f32_16x16x32_bf16(a1[k], b, acc[k][1][ct], 0, 0, 0);
            }
        }
    }

#pragma unroll
    for (int rt = 0; rt < 2; ++rt) {
#pragma unroll
        for (int i = 0; i < 4; ++i) {
            int n = n0 + w * 32 + rt * 16 + quad * 4 + i;
            if (n >= N) continue;
#pragma unroll
            for (int ct = 0; ct < CT; ++ct) {
                int col = ct * 16 + lr;
                float v0 = fmaxf(acc[0][rt][ct][i] + bias[col], 0.0f);
                float v1 = fmaxf(acc[1][rt][ct][i] + bias[64 + col], 0.0f);
                hh[(size_t)n * 64 + col] = f2bf(0.5f * (v0 + v1));
            }
        }
    }
}

// ===== t1 GEMM layer2, both k fused, epilogue = relu+mean+log_softmax -> d_out f32 =====
__global__ __launch_bounds__(256)
void gemm_t1_l2(const ushort_t* __restrict__ s1, const ushort_t* __restrict__ hh,
                const short* __restrict__ fragbuf, const float* __restrict__ bias /* b2+2*41 */,
                int N, float* __restrict__ out) {
    constexpr int CT = 3, CH = 4;
    const int n0 = blockIdx.x * 128;
    const int t = threadIdx.x;
    const int w = t >> 6, lane = t & 63, quad = lane >> 4, lr = lane & 15;

    int r0 = n0 + w * 32 + lr;
    int m0 = r0 < N ? r0 : N - 1;
    int m1 = (r0 + 16) < N ? (r0 + 16) : N - 1;

    f32x4 acc[2][2][CT];
#pragma unroll
    for (int k = 0; k < 2; ++k)
#pragma unroll
        for (int rt = 0; rt < 2; ++rt)
#pragma unroll
            for (int ct = 0; ct < CT; ++ct) acc[k][rt][ct] = (f32x4){0.f, 0.f, 0.f, 0.f};

#pragma unroll
    for (int c = 0; c < CH; ++c) {
        bf16x8 a0[2], a1[2];
        if (c < 2) {
            int off = c * 32 + quad * 8;
#pragma unroll
            for (int k = 0; k < 2; ++k) {
                a0[k] = *(const bf16x8*)&s1[((size_t)m0 * 2 + k) * 48 + off];
                a1[k] = *(const bf16x8*)&s1[((size_t)m1 * 2 + k) * 48 + off];
            }
        } else {
            int off = (c - 2) * 32 + quad * 8;
            a0[0] = a0[1] = *(const bf16x8*)&hh[(size_t)m0 * 64 + off];
            a1[0] = a1[1] = *(const bf16x8*)&hh[(size_t)m1 * 64 + off];
        }
#pragma unroll
        for (int k = 0; k < 2; ++k) {
            const short* fb = fragbuf + (size_t)k * CH * CT * 512;
#pragma unroll
            for (int ct = 0; ct < CT; ++ct) {
                bf16x8 b = *(const bf16x8*)&fb[((size_t)c * CT + ct) * 512 + lane * 8];
                acc[k][0][ct] = __builtin_amdgcn_mfma_f32_16x16x32_bf16(a0[k], b, acc[k][0][ct], 0, 0, 0);
                acc[k][1][ct] = __builtin_amdgcn_mfma_f32_16x16x32_bf16(a1[k], b, acc[k][1][ct], 0, 0, 0);
            }
        }
    }

    // epilogue: m = 0.5*(relu(acc0+b0)+relu(acc1+b1)); row log_softmax over cols<41
#pragma unroll
    for (int rt = 0; rt < 2; ++rt) {
#pragma unroll
        for (int i = 0; i < 4; ++i) {
            int n = n0 + w * 32 + rt * 16 + quad * 4 + i;
            float m[CT];
            float mx = -1e30f;
#pragma unroll
            for (int ct = 0; ct < CT; ++ct) {
                int col = ct * 16 + lr;
                float b0 = (col < 41) ? bias[col] : 0.0f;
                float b1v = (col < 41) ? bias[41 + col] : 0.0f;
                float v0 = fmaxf(acc[0][rt][ct][i] + b0, 0.0f);
                float v1 = fmaxf(acc[1][rt][ct][i] + b1v, 0.0f);
                m[ct] = 0.5f * (v0 + v1);
                if (col < 41) mx = fmaxf(mx, m[ct]);
            }
            // quad-local reduction (16 lanes share a row)
#pragma unroll
            for (int msk = 1; msk < 16; msk <<= 1) mx = fmaxf(mx, __shfl_xor(mx, msk));
            float s = 0.0f;
#pragma unroll
            for (int ct = 0; ct < CT; ++ct) {
                int col = ct * 16 + lr;
                if (col < 41) s += __expf(m[ct] - mx);
            }
#pragma unroll
            for (int msk = 1; msk < 16; msk <<= 1) s += __shfl_xor(s, msk);
            float ls = __logf(s);
            if (n < N) {
#pragma unroll
                for (int ct = 0; ct < CT; ++ct) {
                    int col = ct * 16 + lr;
                    if (col < 41) out[(size_t)n * 41 + col] = m[ct] - mx - ls;
                }
            }
        }
    }
}

// ==================== CSR gather (bf16 payload, weights from dinv) ====================
template<int PAIRS>
__global__ __launch_bounds__(256)
void gather(const int* __restrict__ rowstart, const int* __restrict__ srcidx,
            const float* __restrict__ dinv, const uint_t* __restrict__ msg,
            const float* __restrict__ pre, uint_t* __restrict__ outH, int FW, int N) {
    int gt = blockIdx.x * 256 + threadIdx.x;
    int n = gt >> 6, lane = gt & 63;
    if (n >= N) return;
    int k, pair;
    if (PAIRS == 32) { k = lane >> 5; pair = lane & 31; }
    else { k = lane / PAIRS; pair = lane - k * PAIRS; }
    if (k >= 2) return;
    int beg = rowstart[n], end = rowstart[n + 1];
    float dn = dinv[n];
    float ax = 0.0f, ay = 0.0f;
    int e = beg;
    for (; e + 3 < end; e += 4) {
        int s0 = srcidx[e], s1 = srcidx[e + 1], s2 = srcidx[e + 2], s3 = srcidx[e + 3];
        float w0 = dinv[s0] * dn, w1 = dinv[s1] * dn, w2 = dinv[s2] * dn, w3 = dinv[s3] * dn;
        uint_t u0 = msg[((size_t)s0 * 2 + k) * PAIRS + pair];
        uint_t u1 = msg[((size_t)s1 * 2 + k) * PAIRS + pair];
        uint_t u2 = msg[((size_t)s2 * 2 + k) * PAIRS + pair];
        uint_t u3 = msg[((size_t)s3 * 2 + k) * PAIRS + pair];
        ax = fmaf(bf2f((ushort_t)u0), w0, ax);
        ay = fmaf(bf2f((ushort_t)(u0 >> 16)), w0, ay);
        ax = fmaf(bf2f((ushort_t)u1), w1, ax);
        ay = fmaf(bf2f((ushort_t)(u1 >> 16)), w1, ay);
        ax = fmaf(bf2f((ushort_t)u2), w2, ax);
        ay = fmaf(bf2f((ushort_t)(u2 >> 16)), w2, ay);
        ax = fmaf(bf2f((ushort_t)u3), w3, ax);
        ay = fmaf(bf2f((ushort_t)(u3 >> 16)), w3, ay);
    }
    for (; e < end; ++e) {
        int s0 = srcidx[e];
        float w0 = dinv[s0] * dn;
        uint_t u0 = msg[((size_t)s0 * 2 + k) * PAIRS + pair];
        ax = fmaf(bf2f((ushort_t)u0), w0, ax);
        ay = fmaf(bf2f((ushort_t)(u0 >> 16)), w0, ay);
    }
    size_t oidx = ((size_t)n * 2 + k) * PAIRS + pair;
    if (pre) {
        const float* p = &pre[((size_t)k * N + n) * FW + 2 * pair];
        outH[oidx] = pack2(fmaxf(p[0] + ax, 0.0f), fmaxf(p[1] + ay, 0.0f));
    } else {
        outH[oidx] = pack2(ax, ay);
    }
}

extern "C" void kernel_launch(void* const* d_in, const int* in_sizes, int n_in,
                              void* d_out, int out_size, void* d_ws, size_t ws_size,
                              hipStream_t stream) {
    const float* x       = (const float*)d_in[0];
    const int*   ei      = (const int*)  d_in[1];
    const float* w1_init = (const float*)d_in[2];
    const float* w1      = (const float*)d_in[3];
    const float* w1_root = (const float*)d_in[4];
    const float* b1      = (const float*)d_in[5];
    const float* w2_init = (const float*)d_in[6];
    const float* w2      = (const float*)d_in[7];
    const float* w2_root = (const float*)d_in[8];
    const float* b2      = (const float*)d_in[9];

    const int Fin1 = 128;
    int N = in_sizes[0] / Fin1;          // 100000
    int E = in_sizes[1] / 2;             // 1600000
    const int* row = ei;
    const int* col = ei + E;

    char* ws = (char*)d_ws;
    size_t off = 0;
    auto carve = [&](size_t bytes) -> void* {
        void* p = ws + off;
        off += (bytes + 255) & ~(size_t)255;
        return p;
    };
    int nblkN = (N + TPB - 1) / TPB;   // 391 (<=512 for one-block scan)
    int*      cnt      = (int*)     carve((size_t)N * 4);
    int*      incl     = (int*)     carve((size_t)N * 4);
    int*      rowstart = (int*)     carve((size_t)(N + 1) * 4);
    int*      bsum     = (int*)     carve((size_t)nblkN * 4);
    float*    dinv     = (float*)   carve((size_t)N * 4);
    int*      pos      = (int*)     carve((size_t)E * 4);
    int*      srcidx   = (int*)     carve((size_t)E * 4);
    short*    swz      = (short*)   carve((size_t)(SWZ_A + SWZ_B + SWZ_C + SWZ_D) * 2);
    ushort_t* xh       = (ushort_t*)carve((size_t)N * 128 * 2);      // bf16 x
    ushort_t* hh       = (ushort_t*)carve((size_t)N * 64 * 2);       // bf16 h
    ushort_t* b16A     = (ushort_t*)carve((size_t)N * 2 * 64 * 2);   // P / agg
    ushort_t* b16B     = (ushort_t*)carve((size_t)N * 2 * 64 * 2);   // out_t
    float*    pre      = (float*)   carve((size_t)2 * N * 64 * 4);   // root pre-activation

    // ---- CSR + norm (atomic-free fill) ----
    hipMemsetAsync(cnt, 0, (size_t)N * 4, stream);
    rank_kernel <<<(E + TPB - 1) / TPB, TPB, 0, stream>>>(col, cnt, pos, E);
    dinv_kernel <<<nblkN, TPB, 0, stream>>>(cnt, dinv, N);
    scan_block  <<<nblkN, TPB, 0, stream>>>(cnt, incl, bsum, N);
    scan_bsums  <<<1, 512, 0, stream>>>(bsum, nblkN);
    finalize_csr<<<nblkN, TPB, 0, stream>>>(incl, bsum, rowstart, N);
    fill_csr    <<<(E + TPB - 1) / TPB, TPB, 0, stream>>>(row, col, rowstart, pos, srcidx, E);

    // ---- weight pre-swizzle + x -> bf16 ----
    int swztot = SWZ_A + SWZ_B + SWZ_C + SWZ_D;
    swz_all<<<(swztot + TPB - 1) / TPB, TPB, 0, stream>>>(w1_init, w1, w1_root,
                                                          w2_init, w2, w2_root, swz);
    int nx4 = N * 128 / 4;
    cvt4_kernel<<<(nx4 + TPB - 1) / TPB, TPB, 0, stream>>>((const float4*)x, (uint2*)xh, nx4);

    dim3 gg2((N + 127) / 128, 2);
    dim3 gg1((N + 127) / 128, 1);
    int ggb = (N * 64 + TPB - 1) / TPB;
    const short* swzA = swz;
    const short* swzB = swz + SWZ_A;
    const short* swzC = swz + SWZ_A + SWZ_B;
    const short* swzD = swz + SWZ_A + SWZ_B + SWZ_C;

    // ---- layer 1 (128 -> 64) ----
    // t0 fused: cols 0-63 -> P0 (b16A, gather layout); cols 64-127 -> pre = x@root0+b1[0]
    gemm_t0<8, 4, 4><<<gg2, TPB, 0, stream>>>(xh, 128, swzA, b1, 64, N, pre, b16A);
    // out1 = relu(pre + A@P0)
    gather<32><<<ggb, TPB, 0, stream>>>(rowstart, srcidx, dinv, (const uint_t*)b16A,
                                        pre, (uint_t*)b16B, 64, N);
    // agg = A@out1
    gather<32><<<ggb, TPB, 0, stream>>>(rowstart, srcidx, dinv, (const uint_t*)b16B,
                                        nullptr, (uint_t*)b16A, 64, N);
    // hh = mean_k(relu(agg@w1 + x@root1 + b1[1]))  (both k fused)
    gemm_t1_l1<<<gg1, TPB, 0, stream>>>(b16A, xh, swzB, b1 + 2 * 64, N, hh);

    // ---- layer 2 (64 -> 41) ----
    gemm_t0<6, 3, 2><<<gg2, TPB, 0, stream>>>(hh, 64, swzC, b2, 41, N, pre, b16A);
    gather<24><<<ggb, TPB, 0, stream>>>(rowstart, srcidx, dinv, (const uint_t*)b16A,
                                        pre, (uint_t*)b16B, 48, N);
    gather<24><<<ggb, TPB, 0, stream>>>(rowstart, srcidx, dinv, (const uint_t*)b16B,
                                        nullptr, (uint_t*)b16A, 48, N);
    // d_out = log_softmax(mean_k(relu(agg@w2 + h@root1 + b2[1])))
    gemm_t1_l2<<<gg1, TPB, 0, stream>>>(b16A, hh, swzD, b2 + 2 * 41, N, (float*)d_out);
}